// Round 1
// baseline (340.174 us; speedup 1.0000x reference)
//
#include <hip/hip_runtime.h>

#define DEV __device__ __forceinline__

typedef unsigned short u16;
typedef __attribute__((ext_vector_type(8))) short bf16x8;
typedef __attribute__((ext_vector_type(4))) float f32x4;

// round-to-nearest-even f32 -> bf16
DEV u16 f2bf(float f) {
  union { float f; unsigned u; } un; un.f = f;
  unsigned r = un.u + 0x7fffu + ((un.u >> 16) & 1u);
  return (u16)(r >> 16);
}

DEV void gload16(const void* g, void* l) {
  __builtin_amdgcn_global_load_lds((const __attribute__((address_space(1))) void*)g,
                                   (__attribute__((address_space(3))) void*)l, 16, 0, 0);
}

DEV float blk_sum(float v, volatile float* sb) {
#pragma unroll
  for (int o = 32; o; o >>= 1) v += __shfl_xor(v, o);
  __syncthreads();
  if ((threadIdx.x & 63) == 0) sb[threadIdx.x >> 6] = v;
  __syncthreads();
  return sb[0] + sb[1] + sb[2] + sb[3];
}

DEV float blk_max(float v, volatile float* sb) {
#pragma unroll
  for (int o = 32; o; o >>= 1) v = fmaxf(v, __shfl_xor(v, o));
  __syncthreads();
  if ((threadIdx.x & 63) == 0) sb[threadIdx.x >> 6] = v;
  __syncthreads();
  return fmaxf(fmaxf(sb[0], sb[1]), fmaxf(sb[2], sb[3]));
}

// ---------------- LayerNorm (row = 768) -> bf16 ----------------
__global__ __launch_bounds__(256) void ln_kernel(const float* __restrict__ x,
                                                 const float* __restrict__ g,
                                                 const float* __restrict__ b,
                                                 u16* __restrict__ y) {
  __shared__ float sb[4];
  const size_t row = blockIdx.x;
  const float* xr = x + row * 768;
  const int t = threadIdx.x;
  float v0 = xr[t], v1 = xr[t + 256], v2 = xr[t + 512];
  float mean = blk_sum(v0 + v1 + v2, sb) * (1.0f / 768.0f);
  float d0 = v0 - mean, d1 = v1 - mean, d2 = v2 - mean;
  float var = blk_sum(d0 * d0 + d1 * d1 + d2 * d2, sb) * (1.0f / 768.0f);
  float inv = rsqrtf(var + 1e-5f);
  u16* yr = y + row * 768;
  yr[t]       = f2bf(d0 * inv * g[t]       + b[t]);
  yr[t + 256] = f2bf(d1 * inv * g[t + 256] + b[t + 256]);
  yr[t + 512] = f2bf(d2 * inv * g[t + 512] + b[t + 512]);
}

// ---------------- weight transpose+convert: in[K][N] f32 -> out[N][K] bf16 ----------------
__global__ __launch_bounds__(256) void wt_transpose(const float* __restrict__ in,
                                                    u16* __restrict__ out, int K, int N) {
  __shared__ float tile[32][33];
  const int tx = threadIdx.x & 31, ty = threadIdx.x >> 5;
  const int n0 = blockIdx.x * 32, k0 = blockIdx.y * 32;
#pragma unroll
  for (int i = 0; i < 4; i++)
    tile[ty + 8 * i][tx] = in[(size_t)(k0 + ty + 8 * i) * N + n0 + tx];
  __syncthreads();
#pragma unroll
  for (int i = 0; i < 4; i++)
    out[(size_t)(n0 + ty + 8 * i) * K + k0 + tx] = f2bf(tile[tx][ty + 8 * i]);
}

// ---------------- V transpose: qkv v-slice [b,s,h,d] -> vT [(b*12+h)*64+d][1024] ----------------
__global__ __launch_bounds__(256) void v_transpose(const u16* __restrict__ qkv,
                                                   u16* __restrict__ vT) {
  __shared__ u16 tile[32][33];
  const int tx = threadIdx.x & 31, ty = threadIdx.x >> 5;
  const int z = blockIdx.z, b = z / 12, h = z % 12;
  const int s0 = blockIdx.x * 32, d0 = blockIdx.y * 32;
#pragma unroll
  for (int i = 0; i < 4; i++)
    tile[ty + 8 * i][tx] =
        qkv[(size_t)(b * 1024 + s0 + ty + 8 * i) * 2304 + 1536 + h * 64 + d0 + tx];
  __syncthreads();
#pragma unroll
  for (int i = 0; i < 4; i++)
    vT[(size_t)(z * 64 + d0 + ty + 8 * i) * 1024 + s0 + tx] = tile[tx][ty + 8 * i];
}

// ---------------- poly_norm over rows of scores [24576][1024] f32, bf16 out in-place ----------------
__global__ __launch_bounds__(256) void poly_kernel(float* __restrict__ scores) {
  __shared__ float sb[4];
  const size_t row = blockIdx.x;
  float* sr = scores + row * 1024;
  const int t = threadIdx.x;
  float xs[4];
#pragma unroll
  for (int e = 0; e < 4; e++) xs[e] = sr[e * 256 + t];
  float mx = fmaxf(fmaxf(xs[0], xs[1]), fmaxf(xs[2], xs[3]));
  float c = -blk_max(mx, sb) - 1.0f;
#pragma unroll 1
  for (int it = 0; it < 6; it++) {
    float s2 = 0.f, s3 = 0.f;
#pragma unroll
    for (int e = 0; e < 4; e++) {
      float base = -xs[e] - c;
      float tt = 1.0f / base;
      float t2 = tt * tt;
      s2 += t2;
      s3 += t2 * tt;
    }
    s2 = blk_sum(s2, sb);
    s3 = blk_sum(s3, sb);
    c -= (s2 - 1.0f) / (2.0f * s3 + 1e-8f);
  }
  u16* wr = (u16*)scores + row * 2048;  // in-place bf16, row stride 2048 elems
#pragma unroll
  for (int e = 0; e < 4; e++) {
    float base = -xs[e] - c;
    float tt = 1.0f / base;
    wr[e * 256 + t] = f2bf(tt * tt);
  }
}

// ---------------- generic MFMA GEMM: C = A[M][K] * Bt[N][K]^T, 128 x (32*WN) tile ----------------
// EPI: 0=fused QKV (bias-select + q scale, bf16 out), 1=f32 plain, 2=bf16 plain,
//      3=f32 + bias + residual, 4=GELU(acc+bias) bf16
template <int WN, int EPI>
__global__ __launch_bounds__(256) void gemm_bt(
    const u16* __restrict__ A, int lda, long long sAb, long long sAh,
    const u16* __restrict__ B0, const u16* __restrict__ B1, const u16* __restrict__ B2,
    int ldb, long long sBb, long long sBh,
    void* __restrict__ Cv, int ldc, long long sCb, long long sCh,
    const float* __restrict__ bias0, const float* __restrict__ bias1,
    const float* __restrict__ bias2, const float* __restrict__ res, int K) {
  constexpr int BN = 32 * WN;
  __shared__ __align__(16) u16 lds_a[128 * 32];
  __shared__ __align__(16) u16 lds_b[BN * 32];

  const int zb = blockIdx.z / 12, zh = blockIdx.z % 12;
  A += zb * sAb + zh * sAh;

  const int colbase = blockIdx.y * BN;
  const u16* B = B0;
  const float* bias = bias0;
  int biasoff = 0;
  float qscale = 1.0f;
  if (EPI == 0) {
    int sel = colbase / 768;
    B = (sel == 0) ? B0 : ((sel == 1) ? B1 : B2);
    bias = (sel == 0) ? bias0 : ((sel == 1) ? bias1 : bias2);
    biasoff = sel * 768;
    qscale = (sel == 0) ? 0.125f : 1.0f;  // 1/sqrt(64) on q only
  }
  B += zb * sBb + zh * sBh;

  const char* Abase = (const char*)(A + (size_t)blockIdx.x * 128 * lda);
  const char* Bbase = (const char*)(B + (size_t)(colbase - biasoff) * ldb);
  const int tid = threadIdx.x;
  const size_t ldab = (size_t)lda * 2, ldbb = (size_t)ldb * 2;

  f32x4 acc[4][WN];
#pragma unroll
  for (int m = 0; m < 4; m++)
#pragma unroll
    for (int n = 0; n < WN; n++) acc[m][n] = (f32x4){0.f, 0.f, 0.f, 0.f};

  const int w = tid >> 6, l = tid & 63;
  const int wm = w >> 1, wn = w & 1;
  const int lr = l & 15, kg = l >> 4;

  for (int k0 = 0; k0 < K; k0 += 32) {
#pragma unroll
    for (int j = 0; j < 2; j++) {  // stage A: 128x32 bf16 = 8KB
      int lin = (j * 256 + tid) * 16;
      gload16(Abase + (size_t)(lin >> 6) * ldab + k0 * 2 + (lin & 63), (char*)lds_a + lin);
    }
#pragma unroll
    for (int j = 0; j < BN / 64; j++) {  // stage B: BNx32 bf16
      int lin = (j * 256 + tid) * 16;
      gload16(Bbase + (size_t)(lin >> 6) * ldbb + k0 * 2 + (lin & 63), (char*)lds_b + lin);
    }
    __syncthreads();

    bf16x8 af[4], bfr[WN];
#pragma unroll
    for (int m = 0; m < 4; m++)
      af[m] = *(const bf16x8*)&lds_a[(wm * 64 + m * 16 + lr) * 32 + kg * 8];
#pragma unroll
    for (int n = 0; n < WN; n++)
      bfr[n] = *(const bf16x8*)&lds_b[(wn * WN * 16 + n * 16 + lr) * 32 + kg * 8];
#pragma unroll
    for (int m = 0; m < 4; m++)
#pragma unroll
      for (int n = 0; n < WN; n++)
        acc[m][n] = __builtin_amdgcn_mfma_f32_16x16x32_bf16(af[m], bfr[n], acc[m][n], 0, 0, 0);
    __syncthreads();
  }

  const int row0 = blockIdx.x * 128 + wm * 64 + kg * 4;
  const int colb = colbase + wn * WN * 16;
  float* Cf = (float*)Cv + (size_t)zb * sCb + (size_t)zh * sCh;
  u16* Cu = (u16*)Cv + (size_t)zb * sCb + (size_t)zh * sCh;
#pragma unroll
  for (int m = 0; m < 4; m++) {
#pragma unroll
    for (int n = 0; n < WN; n++) {
#pragma unroll
      for (int r = 0; r < 4; r++) {
        int row = row0 + m * 16 + r;
        int col = colb + n * 16 + lr;
        size_t idx = (size_t)row * ldc + col;
        float v = acc[m][n][r];
        if (EPI == 0) {
          Cu[idx] = f2bf((v + bias[col - biasoff]) * qscale);
        } else if (EPI == 1) {
          Cf[idx] = v;
        } else if (EPI == 2) {
          Cu[idx] = f2bf(v);
        } else if (EPI == 3) {
          Cf[idx] = v + bias[col] + res[idx];
        } else {  // exact GELU
          v += bias[col];
          Cu[idx] = f2bf(0.5f * v * (1.0f + erff(v * 0.70710678118654752f)));
        }
      }
    }
  }
}

extern "C" void kernel_launch(void* const* d_in, const int* in_sizes, int n_in,
                              void* d_out, int out_size, void* d_ws, size_t ws_size,
                              hipStream_t stream) {
  const float* x     = (const float*)d_in[0];
  const float* ln1_g = (const float*)d_in[1];
  const float* ln1_b = (const float*)d_in[2];
  const float* wq    = (const float*)d_in[3];
  const float* bq    = (const float*)d_in[4];
  const float* wk    = (const float*)d_in[5];
  const float* bk    = (const float*)d_in[6];
  const float* wv    = (const float*)d_in[7];
  const float* bv    = (const float*)d_in[8];
  const float* wo    = (const float*)d_in[9];
  const float* bo    = (const float*)d_in[10];
  const float* ln2_g = (const float*)d_in[11];
  const float* ln2_b = (const float*)d_in[12];
  const float* w1    = (const float*)d_in[13];
  const float* b1    = (const float*)d_in[14];
  const float* w2    = (const float*)d_in[15];
  const float* b2    = (const float*)d_in[16];
  float* out = (float*)d_out;

  char* p = (char*)d_ws;
  auto alloc = [&](size_t n) { char* r = p; p += (n + 255) & ~(size_t)255; return r; };
  u16*   qkv    = (u16*)  alloc(2048ull * 2304 * 2);       // [b*1024+s][2304] q|k|v bf16
  float* scores = (float*)alloc(24ull * 1024 * 1024 * 4);  // [b*12+h][1024][1024] f32 (-> bf16 in-place)
  u16*   y1     = (u16*)  alloc(2048ull * 768 * 2);
  u16*   vT     = (u16*)  alloc(24ull * 64 * 1024 * 2);    // [(b*12+h)*64+d][1024]
  u16*   attn   = (u16*)  alloc(2048ull * 768 * 2);
  float* x1     = (float*)alloc(2048ull * 768 * 4);
  u16*   y2     = (u16*)  alloc(2048ull * 768 * 2);
  u16*   hbuf   = (u16*)  alloc(2048ull * 3072 * 2);
  u16*   wq_t   = (u16*)  alloc(768ull * 768 * 2);
  u16*   wk_t   = (u16*)  alloc(768ull * 768 * 2);
  u16*   wv_t   = (u16*)  alloc(768ull * 768 * 2);
  u16*   wo_t   = (u16*)  alloc(768ull * 768 * 2);
  u16*   w1_t   = (u16*)  alloc(3072ull * 768 * 2);
  u16*   w2_t   = (u16*)  alloc(768ull * 3072 * 2);
  (void)in_sizes; (void)n_in; (void)out_size; (void)ws_size;

  // weights -> bf16 [N][K]
  wt_transpose<<<dim3(24, 24), 256, 0, stream>>>(wq, wq_t, 768, 768);
  wt_transpose<<<dim3(24, 24), 256, 0, stream>>>(wk, wk_t, 768, 768);
  wt_transpose<<<dim3(24, 24), 256, 0, stream>>>(wv, wv_t, 768, 768);
  wt_transpose<<<dim3(24, 24), 256, 0, stream>>>(wo, wo_t, 768, 768);
  wt_transpose<<<dim3(96, 24), 256, 0, stream>>>(w1, w1_t, 768, 3072);
  wt_transpose<<<dim3(24, 96), 256, 0, stream>>>(w2, w2_t, 3072, 768);

  // LN1
  ln_kernel<<<2048, 256, 0, stream>>>(x, ln1_g, ln1_b, y1);

  // fused QKV projection: [2048,768] x [768,2304] -> qkv bf16 (q scaled by 1/8)
  gemm_bt<4, 0><<<dim3(16, 18, 1), 256, 0, stream>>>(
      y1, 768, 0, 0, wq_t, wk_t, wv_t, 768, 0, 0, qkv, 2304, 0, 0, bq, bk, bv, nullptr, 768);

  // scores[b,h] = q[b,:,h,:] @ k[b,:,h,:]^T   (M=N=1024, K=64)
  gemm_bt<4, 1><<<dim3(8, 8, 24), 256, 0, stream>>>(
      qkv, 2304, 2359296LL, 64LL, qkv + 768, nullptr, nullptr, 2304, 2359296LL, 64LL,
      scores, 1024, 12582912LL, 1048576LL, nullptr, nullptr, nullptr, nullptr, 64);

  // V transpose
  v_transpose<<<dim3(32, 2, 24), 256, 0, stream>>>(qkv, vT);

  // poly normalizer (Newton x6), bf16 weights in place
  poly_kernel<<<24576, 256, 0, stream>>>(scores);

  // attn[b,:,h,:] = attn_w[b,h] @ v[b,:,h,:]   (M=1024, N=64, K=1024)
  gemm_bt<2, 2><<<dim3(8, 1, 24), 256, 0, stream>>>(
      (const u16*)scores, 2048, 25165824LL, 2097152LL, vT, nullptr, nullptr, 1024,
      786432LL, 65536LL, attn, 768, 786432LL, 64LL, nullptr, nullptr, nullptr, nullptr, 1024);

  // x1 = x + attn @ wo + bo
  gemm_bt<4, 3><<<dim3(16, 6, 1), 256, 0, stream>>>(
      attn, 768, 0, 0, wo_t, nullptr, nullptr, 768, 0, 0, x1, 768, 0, 0,
      bo, nullptr, nullptr, x, 768);

  // LN2
  ln_kernel<<<2048, 256, 0, stream>>>(x1, ln2_g, ln2_b, y2);

  // h = gelu(y2 @ w1 + b1)
  gemm_bt<4, 4><<<dim3(16, 24, 1), 256, 0, stream>>>(
      y2, 768, 0, 0, w1_t, nullptr, nullptr, 768, 0, 0, hbuf, 3072, 0, 0,
      b1, nullptr, nullptr, nullptr, 768);

  // out = x1 + h @ w2 + b2
  gemm_bt<4, 3><<<dim3(16, 6, 1), 256, 0, stream>>>(
      hbuf, 3072, 0, 0, w2_t, nullptr, nullptr, 3072, 0, 0, out, 768, 0, 0,
      b2, nullptr, nullptr, x1, 3072);
}

// Round 2
// 258.646 us; speedup vs baseline: 1.3152x; 1.3152x over previous
//
#include <hip/hip_runtime.h>

#define DEV __device__ __forceinline__

typedef unsigned short u16;
typedef __attribute__((ext_vector_type(8))) short bf16x8;
typedef __attribute__((ext_vector_type(4))) float f32x4;
typedef __attribute__((ext_vector_type(4))) unsigned int u32x4;

// round-to-nearest-even f32 -> bf16
DEV u16 f2bf(float f) {
  union { float f; unsigned u; } un; un.f = f;
  unsigned r = un.u + 0x7fffu + ((un.u >> 16) & 1u);
  return (u16)(r >> 16);
}

DEV void gload16(const void* g, void* l) {
  __builtin_amdgcn_global_load_lds((const __attribute__((address_space(1))) void*)g,
                                   (__attribute__((address_space(3))) void*)l, 16, 0, 0);
}

DEV float blk_sum(float v, volatile float* sb) {
#pragma unroll
  for (int o = 32; o; o >>= 1) v += __shfl_xor(v, o);
  __syncthreads();
  if ((threadIdx.x & 63) == 0) sb[threadIdx.x >> 6] = v;
  __syncthreads();
  return sb[0] + sb[1] + sb[2] + sb[3];
}

// ---------------- LayerNorm (row = 768) -> bf16 ----------------
__global__ __launch_bounds__(256) void ln_kernel(const float* __restrict__ x,
                                                 const float* __restrict__ g,
                                                 const float* __restrict__ b,
                                                 u16* __restrict__ y) {
  __shared__ float sb[4];
  const size_t row = blockIdx.x;
  const float* xr = x + row * 768;
  const int t = threadIdx.x;
  float v0 = xr[t], v1 = xr[t + 256], v2 = xr[t + 512];
  float mean = blk_sum(v0 + v1 + v2, sb) * (1.0f / 768.0f);
  float d0 = v0 - mean, d1 = v1 - mean, d2 = v2 - mean;
  float var = blk_sum(d0 * d0 + d1 * d1 + d2 * d2, sb) * (1.0f / 768.0f);
  float inv = rsqrtf(var + 1e-5f);
  u16* yr = y + row * 768;
  yr[t]       = f2bf(d0 * inv * g[t]       + b[t]);
  yr[t + 256] = f2bf(d1 * inv * g[t + 256] + b[t + 256]);
  yr[t + 512] = f2bf(d2 * inv * g[t + 512] + b[t + 512]);
}

// ---------------- weight transpose+convert: in[K][N] f32 -> out[N][K] bf16 ----------------
__global__ __launch_bounds__(256) void wt_transpose(const float* __restrict__ in,
                                                    u16* __restrict__ out, int K, int N) {
  __shared__ float tile[32][33];
  const int tx = threadIdx.x & 31, ty = threadIdx.x >> 5;
  const int n0 = blockIdx.x * 32, k0 = blockIdx.y * 32;
#pragma unroll
  for (int i = 0; i < 4; i++)
    tile[ty + 8 * i][tx] = in[(size_t)(k0 + ty + 8 * i) * N + n0 + tx];
  __syncthreads();
#pragma unroll
  for (int i = 0; i < 4; i++)
    out[(size_t)(n0 + ty + 8 * i) * K + k0 + tx] = f2bf(tile[tx][ty + 8 * i]);
}

// ---------------- V transpose: qkv v-slice [b,s,h,d] -> vT [(b*12+h)*64+d][1024] ----------------
__global__ __launch_bounds__(256) void v_transpose(const u16* __restrict__ qkv,
                                                   u16* __restrict__ vT) {
  __shared__ u16 tile[32][33];
  const int tx = threadIdx.x & 31, ty = threadIdx.x >> 5;
  const int z = blockIdx.z, b = z / 12, h = z % 12;
  const int s0 = blockIdx.x * 32, d0 = blockIdx.y * 32;
#pragma unroll
  for (int i = 0; i < 4; i++)
    tile[ty + 8 * i][tx] =
        qkv[(size_t)(b * 1024 + s0 + ty + 8 * i) * 2304 + 1536 + h * 64 + d0 + tx];
  __syncthreads();
#pragma unroll
  for (int i = 0; i < 4; i++)
    vT[(size_t)(z * 64 + d0 + ty + 8 * i) * 1024 + s0 + tx] = tile[tx][ty + 8 * i];
}

// ---------------- poly_norm: one row (1024 f32) per 64-lane wave, bf16 out in-place --------
// Lane l holds row[l*16 .. l*16+15] in registers. All reductions are pure shfl_xor
// (no LDS, no barriers). All reciprocals are v_rcp_f32 (~1 ulp; output is bf16).
__global__ __launch_bounds__(256) void poly_kernel(float* __restrict__ scores) {
  const int wid = threadIdx.x >> 6, l = threadIdx.x & 63;
  const size_t row = (size_t)blockIdx.x * 4 + wid;
  float* sr = scores + row * 1024;

  f32x4 xv[4];
#pragma unroll
  for (int j = 0; j < 4; j++) xv[j] = *(const f32x4*)&sr[l * 16 + j * 4];

  float mx = -3.4e38f;
#pragma unroll
  for (int j = 0; j < 4; j++)
#pragma unroll
    for (int e = 0; e < 4; e++) mx = fmaxf(mx, xv[j][e]);
#pragma unroll
  for (int o = 32; o; o >>= 1) mx = fmaxf(mx, __shfl_xor(mx, o));
  float c = -mx - 1.0f;  // == min(-x) - 1

#pragma unroll 1
  for (int it = 0; it < 6; it++) {
    float s2 = 0.f, s3 = 0.f;
#pragma unroll
    for (int j = 0; j < 4; j++)
#pragma unroll
      for (int e = 0; e < 4; e++) {
        float r = __builtin_amdgcn_rcpf(-xv[j][e] - c);
        float r2 = r * r;
        s2 += r2;
        s3 = fmaf(r2, r, s3);
      }
#pragma unroll
    for (int o = 32; o; o >>= 1) {
      s2 += __shfl_xor(s2, o);
      s3 += __shfl_xor(s3, o);
    }
    c -= (s2 - 1.0f) * __builtin_amdgcn_rcpf(2.0f * s3 + 1e-8f);
  }

  // weights = rcp(base)^2 -> bf16, packed 32B/lane, in-place (row stride 2048 u16)
  unsigned wbuf[8];
#pragma unroll
  for (int j = 0; j < 4; j++)
#pragma unroll
    for (int e = 0; e < 2; e++) {
      float r0 = __builtin_amdgcn_rcpf(-xv[j][2 * e] - c);
      float r1 = __builtin_amdgcn_rcpf(-xv[j][2 * e + 1] - c);
      wbuf[j * 2 + e] = (unsigned)f2bf(r0 * r0) | ((unsigned)f2bf(r1 * r1) << 16);
    }
  u16* wr = (u16*)scores + row * 2048 + l * 16;
  *(u32x4*)wr = (u32x4){wbuf[0], wbuf[1], wbuf[2], wbuf[3]};
  *(u32x4*)(wr + 8) = (u32x4){wbuf[4], wbuf[5], wbuf[6], wbuf[7]};
}

// ---------------- generic MFMA GEMM: C = A[M][K] * Bt[N][K]^T, 128 x (32*WN) tile ----------------
// EPI: 0=fused QKV (bias-select + q scale, bf16 out), 1=f32 plain, 2=bf16 plain,
//      3=f32 + bias + residual, 4=GELU(acc+bias) bf16
template <int WN, int EPI>
__global__ __launch_bounds__(256) void gemm_bt(
    const u16* __restrict__ A, int lda, long long sAb, long long sAh,
    const u16* __restrict__ B0, const u16* __restrict__ B1, const u16* __restrict__ B2,
    int ldb, long long sBb, long long sBh,
    void* __restrict__ Cv, int ldc, long long sCb, long long sCh,
    const float* __restrict__ bias0, const float* __restrict__ bias1,
    const float* __restrict__ bias2, const float* __restrict__ res, int K) {
  constexpr int BN = 32 * WN;
  __shared__ __align__(16) u16 lds_a[128 * 32];
  __shared__ __align__(16) u16 lds_b[BN * 32];

  const int zb = blockIdx.z / 12, zh = blockIdx.z % 12;
  A += zb * sAb + zh * sAh;

  const int colbase = blockIdx.y * BN;
  const u16* B = B0;
  const float* bias = bias0;
  int biasoff = 0;
  float qscale = 1.0f;
  if (EPI == 0) {
    int sel = colbase / 768;
    B = (sel == 0) ? B0 : ((sel == 1) ? B1 : B2);
    bias = (sel == 0) ? bias0 : ((sel == 1) ? bias1 : bias2);
    biasoff = sel * 768;
    qscale = (sel == 0) ? 0.125f : 1.0f;  // 1/sqrt(64) on q only
  }
  B += zb * sBb + zh * sBh;

  const char* Abase = (const char*)(A + (size_t)blockIdx.x * 128 * lda);
  const char* Bbase = (const char*)(B + (size_t)(colbase - biasoff) * ldb);
  const int tid = threadIdx.x;
  const size_t ldab = (size_t)lda * 2, ldbb = (size_t)ldb * 2;

  f32x4 acc[4][WN];
#pragma unroll
  for (int m = 0; m < 4; m++)
#pragma unroll
    for (int n = 0; n < WN; n++) acc[m][n] = (f32x4){0.f, 0.f, 0.f, 0.f};

  const int w = tid >> 6, l = tid & 63;
  const int wm = w >> 1, wn = w & 1;
  const int lr = l & 15, kg = l >> 4;

  for (int k0 = 0; k0 < K; k0 += 32) {
#pragma unroll
    for (int j = 0; j < 2; j++) {  // stage A: 128x32 bf16 = 8KB
      int lin = (j * 256 + tid) * 16;
      gload16(Abase + (size_t)(lin >> 6) * ldab + k0 * 2 + (lin & 63), (char*)lds_a + lin);
    }
#pragma unroll
    for (int j = 0; j < BN / 64; j++) {  // stage B: BNx32 bf16
      int lin = (j * 256 + tid) * 16;
      gload16(Bbase + (size_t)(lin >> 6) * ldbb + k0 * 2 + (lin & 63), (char*)lds_b + lin);
    }
    __syncthreads();

    bf16x8 af[4], bfr[WN];
#pragma unroll
    for (int m = 0; m < 4; m++)
      af[m] = *(const bf16x8*)&lds_a[(wm * 64 + m * 16 + lr) * 32 + kg * 8];
#pragma unroll
    for (int n = 0; n < WN; n++)
      bfr[n] = *(const bf16x8*)&lds_b[(wn * WN * 16 + n * 16 + lr) * 32 + kg * 8];
#pragma unroll
    for (int m = 0; m < 4; m++)
#pragma unroll
      for (int n = 0; n < WN; n++)
        acc[m][n] = __builtin_amdgcn_mfma_f32_16x16x32_bf16(af[m], bfr[n], acc[m][n], 0, 0, 0);
    __syncthreads();
  }

  const int row0 = blockIdx.x * 128 + wm * 64 + kg * 4;
  const int colb = colbase + wn * WN * 16;
  float* Cf = (float*)Cv + (size_t)zb * sCb + (size_t)zh * sCh;
  u16* Cu = (u16*)Cv + (size_t)zb * sCb + (size_t)zh * sCh;
#pragma unroll
  for (int m = 0; m < 4; m++) {
#pragma unroll
    for (int n = 0; n < WN; n++) {
#pragma unroll
      for (int r = 0; r < 4; r++) {
        int row = row0 + m * 16 + r;
        int col = colb + n * 16 + lr;
        size_t idx = (size_t)row * ldc + col;
        float v = acc[m][n][r];
        if (EPI == 0) {
          Cu[idx] = f2bf((v + bias[col - biasoff]) * qscale);
        } else if (EPI == 1) {
          Cf[idx] = v;
        } else if (EPI == 2) {
          Cu[idx] = f2bf(v);
        } else if (EPI == 3) {
          Cf[idx] = v + bias[col] + res[idx];
        } else {  // exact GELU
          v += bias[col];
          Cu[idx] = f2bf(0.5f * v * (1.0f + erff(v * 0.70710678118654752f)));
        }
      }
    }
  }
}

extern "C" void kernel_launch(void* const* d_in, const int* in_sizes, int n_in,
                              void* d_out, int out_size, void* d_ws, size_t ws_size,
                              hipStream_t stream) {
  const float* x     = (const float*)d_in[0];
  const float* ln1_g = (const float*)d_in[1];
  const float* ln1_b = (const float*)d_in[2];
  const float* wq    = (const float*)d_in[3];
  const float* bq    = (const float*)d_in[4];
  const float* wk    = (const float*)d_in[5];
  const float* bk    = (const float*)d_in[6];
  const float* wv    = (const float*)d_in[7];
  const float* bv    = (const float*)d_in[8];
  const float* wo    = (const float*)d_in[9];
  const float* bo    = (const float*)d_in[10];
  const float* ln2_g = (const float*)d_in[11];
  const float* ln2_b = (const float*)d_in[12];
  const float* w1    = (const float*)d_in[13];
  const float* b1    = (const float*)d_in[14];
  const float* w2    = (const float*)d_in[15];
  const float* b2    = (const float*)d_in[16];
  float* out = (float*)d_out;

  char* p = (char*)d_ws;
  auto alloc = [&](size_t n) { char* r = p; p += (n + 255) & ~(size_t)255; return r; };
  u16*   qkv    = (u16*)  alloc(2048ull * 2304 * 2);       // [b*1024+s][2304] q|k|v bf16
  float* scores = (float*)alloc(24ull * 1024 * 1024 * 4);  // [b*12+h][1024][1024] f32 (-> bf16 in-place)
  u16*   y1     = (u16*)  alloc(2048ull * 768 * 2);
  u16*   vT     = (u16*)  alloc(24ull * 64 * 1024 * 2);    // [(b*12+h)*64+d][1024]
  u16*   attn   = (u16*)  alloc(2048ull * 768 * 2);
  float* x1     = (float*)alloc(2048ull * 768 * 4);
  u16*   y2     = (u16*)  alloc(2048ull * 768 * 2);
  u16*   hbuf   = (u16*)  alloc(2048ull * 3072 * 2);
  u16*   wq_t   = (u16*)  alloc(768ull * 768 * 2);
  u16*   wk_t   = (u16*)  alloc(768ull * 768 * 2);
  u16*   wv_t   = (u16*)  alloc(768ull * 768 * 2);
  u16*   wo_t   = (u16*)  alloc(768ull * 768 * 2);
  u16*   w1_t   = (u16*)  alloc(3072ull * 768 * 2);
  u16*   w2_t   = (u16*)  alloc(768ull * 3072 * 2);
  (void)in_sizes; (void)n_in; (void)out_size; (void)ws_size;

  // weights -> bf16 [N][K]
  wt_transpose<<<dim3(24, 24), 256, 0, stream>>>(wq, wq_t, 768, 768);
  wt_transpose<<<dim3(24, 24), 256, 0, stream>>>(wk, wk_t, 768, 768);
  wt_transpose<<<dim3(24, 24), 256, 0, stream>>>(wv, wv_t, 768, 768);
  wt_transpose<<<dim3(24, 24), 256, 0, stream>>>(wo, wo_t, 768, 768);
  wt_transpose<<<dim3(96, 24), 256, 0, stream>>>(w1, w1_t, 768, 3072);
  wt_transpose<<<dim3(24, 96), 256, 0, stream>>>(w2, w2_t, 3072, 768);

  // LN1
  ln_kernel<<<2048, 256, 0, stream>>>(x, ln1_g, ln1_b, y1);

  // fused QKV projection: [2048,768] x [768,2304] -> qkv bf16 (q scaled by 1/8)
  gemm_bt<4, 0><<<dim3(16, 18, 1), 256, 0, stream>>>(
      y1, 768, 0, 0, wq_t, wk_t, wv_t, 768, 0, 0, qkv, 2304, 0, 0, bq, bk, bv, nullptr, 768);

  // scores[b,h] = q[b,:,h,:] @ k[b,:,h,:]^T   (M=N=1024, K=64)
  gemm_bt<4, 1><<<dim3(8, 8, 24), 256, 0, stream>>>(
      qkv, 2304, 2359296LL, 64LL, qkv + 768, nullptr, nullptr, 2304, 2359296LL, 64LL,
      scores, 1024, 12582912LL, 1048576LL, nullptr, nullptr, nullptr, nullptr, 64);

  // V transpose
  v_transpose<<<dim3(32, 2, 24), 256, 0, stream>>>(qkv, vT);

  // poly normalizer (Newton x6), bf16 weights in place; 4 rows/block (1/wave)
  poly_kernel<<<6144, 256, 0, stream>>>(scores);

  // attn[b,:,h,:] = attn_w[b,h] @ v[b,:,h,:]   (M=1024, N=64, K=1024)
  gemm_bt<2, 2><<<dim3(8, 1, 24), 256, 0, stream>>>(
      (const u16*)scores, 2048, 25165824LL, 2097152LL, vT, nullptr, nullptr, 1024,
      786432LL, 65536LL, attn, 768, 786432LL, 64LL, nullptr, nullptr, nullptr, nullptr, 1024);

  // x1 = x + attn @ wo + bo
  gemm_bt<4, 3><<<dim3(16, 6, 1), 256, 0, stream>>>(
      attn, 768, 0, 0, wo_t, nullptr, nullptr, 768, 0, 0, x1, 768, 0, 0,
      bo, nullptr, nullptr, x, 768);

  // LN2
  ln_kernel<<<2048, 256, 0, stream>>>(x1, ln2_g, ln2_b, y2);

  // h = gelu(y2 @ w1 + b1)
  gemm_bt<4, 4><<<dim3(16, 24, 1), 256, 0, stream>>>(
      y2, 768, 0, 0, w1_t, nullptr, nullptr, 768, 0, 0, hbuf, 3072, 0, 0,
      b1, nullptr, nullptr, nullptr, 768);

  // out = x1 + h @ w2 + b2
  gemm_bt<4, 3><<<dim3(16, 6, 1), 256, 0, stream>>>(
      hbuf, 3072, 0, 0, w2_t, nullptr, nullptr, 3072, 0, 0, out, 768, 0, 0,
      b2, nullptr, nullptr, x1, 3072);
}

// Round 3
// 226.955 us; speedup vs baseline: 1.4989x; 1.1396x over previous
//
#include <hip/hip_runtime.h>

#define DEV __device__ __forceinline__

typedef unsigned short u16;
typedef __attribute__((ext_vector_type(8))) short bf16x8;
typedef __attribute__((ext_vector_type(4))) float f32x4;
typedef __attribute__((ext_vector_type(4))) unsigned int u32x4;

// round-to-nearest-even f32 -> bf16
DEV u16 f2bf(float f) {
  union { float f; unsigned u; } un; un.f = f;
  unsigned r = un.u + 0x7fffu + ((un.u >> 16) & 1u);
  return (u16)(r >> 16);
}

DEV void gload16(const void* g, void* l) {
  __builtin_amdgcn_global_load_lds((const __attribute__((address_space(1))) void*)g,
                                   (__attribute__((address_space(3))) void*)l, 16, 0, 0);
}

template <int N>
DEV void vm_wait() { asm volatile("s_waitcnt vmcnt(%0)" :: "n"(N) : "memory"); }

DEV float blk_sum(float v, volatile float* sb) {
#pragma unroll
  for (int o = 32; o; o >>= 1) v += __shfl_xor(v, o);
  __syncthreads();
  if ((threadIdx.x & 63) == 0) sb[threadIdx.x >> 6] = v;
  __syncthreads();
  return sb[0] + sb[1] + sb[2] + sb[3];
}

// ---------------- LayerNorm (row = 768) -> bf16 ----------------
__global__ __launch_bounds__(256) void ln_kernel(const float* __restrict__ x,
                                                 const float* __restrict__ g,
                                                 const float* __restrict__ b,
                                                 u16* __restrict__ y) {
  __shared__ float sb[4];
  const size_t row = blockIdx.x;
  const float* xr = x + row * 768;
  const int t = threadIdx.x;
  float v0 = xr[t], v1 = xr[t + 256], v2 = xr[t + 512];
  float mean = blk_sum(v0 + v1 + v2, sb) * (1.0f / 768.0f);
  float d0 = v0 - mean, d1 = v1 - mean, d2 = v2 - mean;
  float var = blk_sum(d0 * d0 + d1 * d1 + d2 * d2, sb) * (1.0f / 768.0f);
  float inv = rsqrtf(var + 1e-5f);
  u16* yr = y + row * 768;
  yr[t]       = f2bf(d0 * inv * g[t]       + b[t]);
  yr[t + 256] = f2bf(d1 * inv * g[t + 256] + b[t + 256]);
  yr[t + 512] = f2bf(d2 * inv * g[t + 512] + b[t + 512]);
}

// ---------------- weight transpose+convert: in[K][N] f32 -> out[N][K] bf16 ----------------
__global__ __launch_bounds__(256) void wt_transpose(const float* __restrict__ in,
                                                    u16* __restrict__ out, int K, int N) {
  __shared__ float tile[32][33];
  const int tx = threadIdx.x & 31, ty = threadIdx.x >> 5;
  const int n0 = blockIdx.x * 32, k0 = blockIdx.y * 32;
#pragma unroll
  for (int i = 0; i < 4; i++)
    tile[ty + 8 * i][tx] = in[(size_t)(k0 + ty + 8 * i) * N + n0 + tx];
  __syncthreads();
#pragma unroll
  for (int i = 0; i < 4; i++)
    out[(size_t)(n0 + ty + 8 * i) * K + k0 + tx] = f2bf(tile[tx][ty + 8 * i]);
}

// ---------------- V transpose: qkv v-slice [b,s,h,d] -> vT [(b*12+h)*64+d][1024] ----------------
__global__ __launch_bounds__(256) void v_transpose(const u16* __restrict__ qkv,
                                                   u16* __restrict__ vT) {
  __shared__ u16 tile[32][33];
  const int tx = threadIdx.x & 31, ty = threadIdx.x >> 5;
  const int z = blockIdx.z, b = z / 12, h = z % 12;
  const int s0 = blockIdx.x * 32, d0 = blockIdx.y * 32;
#pragma unroll
  for (int i = 0; i < 4; i++)
    tile[ty + 8 * i][tx] =
        qkv[(size_t)(b * 1024 + s0 + ty + 8 * i) * 2304 + 1536 + h * 64 + d0 + tx];
  __syncthreads();
#pragma unroll
  for (int i = 0; i < 4; i++)
    vT[(size_t)(z * 64 + d0 + ty + 8 * i) * 1024 + s0 + tx] = tile[tx][ty + 8 * i];
}

// ---------------- poly_norm: one row (1024 f32) per 64-lane wave, bf16 out in-place --------
__global__ __launch_bounds__(256) void poly_kernel(float* __restrict__ scores) {
  const int wid = threadIdx.x >> 6, l = threadIdx.x & 63;
  const size_t row = (size_t)blockIdx.x * 4 + wid;
  float* sr = scores + row * 1024;

  f32x4 xv[4];
#pragma unroll
  for (int j = 0; j < 4; j++) xv[j] = *(const f32x4*)&sr[l * 16 + j * 4];

  float mx = -3.4e38f;
#pragma unroll
  for (int j = 0; j < 4; j++)
#pragma unroll
    for (int e = 0; e < 4; e++) mx = fmaxf(mx, xv[j][e]);
#pragma unroll
  for (int o = 32; o; o >>= 1) mx = fmaxf(mx, __shfl_xor(mx, o));
  float c = -mx - 1.0f;  // == min(-x) - 1

#pragma unroll 1
  for (int it = 0; it < 6; it++) {
    float s2 = 0.f, s3 = 0.f;
#pragma unroll
    for (int j = 0; j < 4; j++)
#pragma unroll
      for (int e = 0; e < 4; e++) {
        float r = __builtin_amdgcn_rcpf(-xv[j][e] - c);
        float r2 = r * r;
        s2 += r2;
        s3 = fmaf(r2, r, s3);
      }
#pragma unroll
    for (int o = 32; o; o >>= 1) {
      s2 += __shfl_xor(s2, o);
      s3 += __shfl_xor(s3, o);
    }
    c -= (s2 - 1.0f) * __builtin_amdgcn_rcpf(2.0f * s3 + 1e-8f);
  }

  unsigned wbuf[8];
#pragma unroll
  for (int j = 0; j < 4; j++)
#pragma unroll
    for (int e = 0; e < 2; e++) {
      float r0 = __builtin_amdgcn_rcpf(-xv[j][2 * e] - c);
      float r1 = __builtin_amdgcn_rcpf(-xv[j][2 * e + 1] - c);
      wbuf[j * 2 + e] = (unsigned)f2bf(r0 * r0) | ((unsigned)f2bf(r1 * r1) << 16);
    }
  u16* wr = (u16*)scores + row * 2048 + l * 16;
  *(u32x4*)wr = (u32x4){wbuf[0], wbuf[1], wbuf[2], wbuf[3]};
  *(u32x4*)(wr + 8) = (u32x4){wbuf[4], wbuf[5], wbuf[6], wbuf[7]};
}

// ---------------- pipelined MFMA GEMM: C = A[M][K] * Bt[N][K]^T ----------------
// BM in {64,128}. BM=128: 4 waves as 2x2, BN = 2*WN*16. BM=64: 4 waves as 1x4, BN = 4*WN*16.
// 3-buffer LDS, 2-deep global_load_lds prefetch, counted vmcnt, raw s_barrier (no drain).
// EPI: 0=fused QKV (bias-select + q scale, bf16 out), 1=f32 plain, 2=bf16 plain,
//      3=f32 + bias + residual, 4=GELU(acc+bias) bf16
template <int BM, int WN, int EPI>
__global__ __launch_bounds__(256) void gemm_bt(
    const u16* __restrict__ A, int lda, long long sAb, long long sAh,
    const u16* __restrict__ B0, const u16* __restrict__ B1, const u16* __restrict__ B2,
    int ldb, long long sBb, long long sBh,
    void* __restrict__ Cv, int ldc, long long sCb, long long sCh,
    const float* __restrict__ bias0, const float* __restrict__ bias1,
    const float* __restrict__ bias2, const float* __restrict__ res, int K) {
  constexpr int WCOL = (BM == 128) ? 2 : 4;
  constexpr int BN = WCOL * WN * 16;
  constexpr int NA = BM / 64;  // stage chunks: 256 thr x 16B = 4 KB = 64 rows x 32 bf16
  constexpr int NB = BN / 64;
  constexpr int LT = NA + NB;  // global_load_lds per thread per K-tile
  __shared__ __align__(16) u16 lds_a[3][BM * 32];
  __shared__ __align__(16) u16 lds_b[3][BN * 32];

  const int zb = blockIdx.z / 12, zh = blockIdx.z % 12;
  A += zb * sAb + zh * sAh;

  const int colbase = blockIdx.y * BN;
  const u16* B = B0;
  const float* bias = bias0;
  int biasoff = 0;
  float qscale = 1.0f;
  if (EPI == 0) {
    int sel = colbase / 768;
    B = (sel == 0) ? B0 : ((sel == 1) ? B1 : B2);
    bias = (sel == 0) ? bias0 : ((sel == 1) ? bias1 : bias2);
    biasoff = sel * 768;
    qscale = (sel == 0) ? 0.125f : 1.0f;  // 1/sqrt(64) on q only
  }
  B += zb * sBb + zh * sBh;

  const int tid = threadIdx.x;
  const size_t ldab = (size_t)lda * 2, ldbb = (size_t)ldb * 2;
  const char* Abase = (const char*)(A + (size_t)blockIdx.x * BM * lda);
  const char* Bbase = (const char*)(B + (size_t)(colbase - biasoff) * ldb);

  // per-thread staging pointers, advanced 64B per staged K-tile
  const char* ap[NA];
  const char* bp[NB];
#pragma unroll
  for (int j = 0; j < NA; j++) {
    int lin = (j * 256 + tid) * 16;
    ap[j] = Abase + (size_t)(lin >> 6) * ldab + (lin & 63);
  }
#pragma unroll
  for (int j = 0; j < NB; j++) {
    int lin = (j * 256 + tid) * 16;
    bp[j] = Bbase + (size_t)(lin >> 6) * ldbb + (lin & 63);
  }

  auto stage = [&](int buf) {
#pragma unroll
    for (int j = 0; j < NA; j++) {
      gload16(ap[j], (char*)&lds_a[buf][0] + (j * 256 + tid) * 16);
      ap[j] += 64;
    }
#pragma unroll
    for (int j = 0; j < NB; j++) {
      gload16(bp[j], (char*)&lds_b[buf][0] + (j * 256 + tid) * 16);
      bp[j] += 64;
    }
  };

  f32x4 acc[4][WN];
#pragma unroll
  for (int m = 0; m < 4; m++)
#pragma unroll
    for (int n = 0; n < WN; n++) acc[m][n] = (f32x4){0.f, 0.f, 0.f, 0.f};

  const int w = tid >> 6, l = tid & 63;
  const int wm = (BM == 128) ? (w >> 1) : 0;
  const int wn = (BM == 128) ? (w & 1) : w;
  const int lr = l & 15, kg = l >> 4;

  const int nt = K / 32;
  stage(0);
  if (nt > 1) stage(1);

  for (int t = 0; t < nt; ++t) {
    const int buf = t % 3;
    if (t + 2 < nt) {
      stage((t + 2) % 3);
      vm_wait<2 * LT>();
    } else if (t + 1 < nt) {
      vm_wait<LT>();
    } else {
      vm_wait<0>();
    }
    __builtin_amdgcn_sched_barrier(0);
    __builtin_amdgcn_s_barrier();
    __builtin_amdgcn_sched_barrier(0);

    bf16x8 af[4], bfr[WN];
#pragma unroll
    for (int m = 0; m < 4; m++)
      af[m] = *(const bf16x8*)&lds_a[buf][(wm * 64 + m * 16 + lr) * 32 + kg * 8];
#pragma unroll
    for (int n = 0; n < WN; n++)
      bfr[n] = *(const bf16x8*)&lds_b[buf][(wn * WN * 16 + n * 16 + lr) * 32 + kg * 8];
#pragma unroll
    for (int m = 0; m < 4; m++)
#pragma unroll
      for (int n = 0; n < WN; n++)
        acc[m][n] = __builtin_amdgcn_mfma_f32_16x16x32_bf16(af[m], bfr[n], acc[m][n], 0, 0, 0);

    __builtin_amdgcn_sched_barrier(0);
    __builtin_amdgcn_s_barrier();
    __builtin_amdgcn_sched_barrier(0);
  }

  const int row0 = blockIdx.x * BM + ((BM == 128) ? wm * 64 : 0) + kg * 4;
  const int colb = colbase + wn * WN * 16;
  float* Cf = (float*)Cv + (size_t)zb * sCb + (size_t)zh * sCh;
  u16* Cu = (u16*)Cv + (size_t)zb * sCb + (size_t)zh * sCh;
#pragma unroll
  for (int m = 0; m < 4; m++) {
#pragma unroll
    for (int n = 0; n < WN; n++) {
#pragma unroll
      for (int r = 0; r < 4; r++) {
        int row = row0 + m * 16 + r;
        int col = colb + n * 16 + lr;
        size_t idx = (size_t)row * ldc + col;
        float v = acc[m][n][r];
        if (EPI == 0) {
          Cu[idx] = f2bf((v + bias[col - biasoff]) * qscale);
        } else if (EPI == 1) {
          Cf[idx] = v;
        } else if (EPI == 2) {
          Cu[idx] = f2bf(v);
        } else if (EPI == 3) {
          Cf[idx] = v + bias[col] + res[idx];
        } else {  // exact GELU
          v += bias[col];
          Cu[idx] = f2bf(0.5f * v * (1.0f + erff(v * 0.70710678118654752f)));
        }
      }
    }
  }
}

extern "C" void kernel_launch(void* const* d_in, const int* in_sizes, int n_in,
                              void* d_out, int out_size, void* d_ws, size_t ws_size,
                              hipStream_t stream) {
  const float* x     = (const float*)d_in[0];
  const float* ln1_g = (const float*)d_in[1];
  const float* ln1_b = (const float*)d_in[2];
  const float* wq    = (const float*)d_in[3];
  const float* bq    = (const float*)d_in[4];
  const float* wk    = (const float*)d_in[5];
  const float* bk    = (const float*)d_in[6];
  const float* wv    = (const float*)d_in[7];
  const float* bv    = (const float*)d_in[8];
  const float* wo    = (const float*)d_in[9];
  const float* bo    = (const float*)d_in[10];
  const float* ln2_g = (const float*)d_in[11];
  const float* ln2_b = (const float*)d_in[12];
  const float* w1    = (const float*)d_in[13];
  const float* b1    = (const float*)d_in[14];
  const float* w2    = (const float*)d_in[15];
  const float* b2    = (const float*)d_in[16];
  float* out = (float*)d_out;

  char* p = (char*)d_ws;
  auto alloc = [&](size_t n) { char* r = p; p += (n + 255) & ~(size_t)255; return r; };
  u16*   qkv    = (u16*)  alloc(2048ull * 2304 * 2);       // [b*1024+s][2304] q|k|v bf16
  float* scores = (float*)alloc(24ull * 1024 * 1024 * 4);  // [b*12+h][1024][1024] f32 (-> bf16 in-place)
  u16*   y1     = (u16*)  alloc(2048ull * 768 * 2);
  u16*   vT     = (u16*)  alloc(24ull * 64 * 1024 * 2);    // [(b*12+h)*64+d][1024]
  u16*   attn   = (u16*)  alloc(2048ull * 768 * 2);
  float* x1     = (float*)alloc(2048ull * 768 * 4);
  u16*   y2     = (u16*)  alloc(2048ull * 768 * 2);
  u16*   hbuf   = (u16*)  alloc(2048ull * 3072 * 2);
  u16*   wq_t   = (u16*)  alloc(768ull * 768 * 2);
  u16*   wk_t   = (u16*)  alloc(768ull * 768 * 2);
  u16*   wv_t   = (u16*)  alloc(768ull * 768 * 2);
  u16*   wo_t   = (u16*)  alloc(768ull * 768 * 2);
  u16*   w1_t   = (u16*)  alloc(3072ull * 768 * 2);
  u16*   w2_t   = (u16*)  alloc(768ull * 3072 * 2);
  (void)in_sizes; (void)n_in; (void)out_size; (void)ws_size;

  // weights -> bf16 [N][K]
  wt_transpose<<<dim3(24, 24), 256, 0, stream>>>(wq, wq_t, 768, 768);
  wt_transpose<<<dim3(24, 24), 256, 0, stream>>>(wk, wk_t, 768, 768);
  wt_transpose<<<dim3(24, 24), 256, 0, stream>>>(wv, wv_t, 768, 768);
  wt_transpose<<<dim3(24, 24), 256, 0, stream>>>(wo, wo_t, 768, 768);
  wt_transpose<<<dim3(96, 24), 256, 0, stream>>>(w1, w1_t, 768, 3072);
  wt_transpose<<<dim3(24, 96), 256, 0, stream>>>(w2, w2_t, 3072, 768);

  // LN1
  ln_kernel<<<2048, 256, 0, stream>>>(x, ln1_g, ln1_b, y1);

  // fused QKV projection: [2048,768] x [768,2304] -> qkv bf16 (q scaled by 1/8)
  gemm_bt<128, 4, 0><<<dim3(16, 18, 1), 256, 0, stream>>>(
      y1, 768, 0, 0, wq_t, wk_t, wv_t, 768, 0, 0, qkv, 2304, 0, 0, bq, bk, bv, nullptr, 768);

  // scores[b,h] = q[b,:,h,:] @ k[b,:,h,:]^T   (M=N=1024, K=64)
  gemm_bt<128, 4, 1><<<dim3(8, 8, 24), 256, 0, stream>>>(
      qkv, 2304, 2359296LL, 64LL, qkv + 768, nullptr, nullptr, 2304, 2359296LL, 64LL,
      scores, 1024, 12582912LL, 1048576LL, nullptr, nullptr, nullptr, nullptr, 64);

  // V transpose
  v_transpose<<<dim3(32, 2, 24), 256, 0, stream>>>(qkv, vT);

  // poly normalizer (Newton x6), bf16 weights in place; 1 row/wave
  poly_kernel<<<6144, 256, 0, stream>>>(scores);

  // attn[b,:,h,:] = attn_w[b,h] @ v[b,:,h,:]   (M=1024, N=64, K=1024)
  gemm_bt<64, 1, 2><<<dim3(16, 1, 24), 256, 0, stream>>>(
      (const u16*)scores, 2048, 25165824LL, 2097152LL, vT, nullptr, nullptr, 1024,
      786432LL, 65536LL, attn, 768, 786432LL, 64LL, nullptr, nullptr, nullptr, nullptr, 1024);

  // x1 = x + attn @ wo + bo
  gemm_bt<64, 2, 3><<<dim3(32, 6, 1), 256, 0, stream>>>(
      attn, 768, 0, 0, wo_t, nullptr, nullptr, 768, 0, 0, x1, 768, 0, 0,
      bo, nullptr, nullptr, x, 768);

  // LN2
  ln_kernel<<<2048, 256, 0, stream>>>(x1, ln2_g, ln2_b, y2);

  // h = gelu(y2 @ w1 + b1)
  gemm_bt<128, 4, 4><<<dim3(16, 24, 1), 256, 0, stream>>>(
      y2, 768, 0, 0, w1_t, nullptr, nullptr, 768, 0, 0, hbuf, 3072, 0, 0,
      b1, nullptr, nullptr, nullptr, 768);

  // out = x1 + h @ w2 + b2
  gemm_bt<64, 2, 3><<<dim3(32, 6, 1), 256, 0, stream>>>(
      hbuf, 3072, 0, 0, w2_t, nullptr, nullptr, 3072, 0, 0, out, 768, 0, 0,
      b2, nullptr, nullptr, x1, 3072);
}

// Round 5
// 201.932 us; speedup vs baseline: 1.6846x; 1.1239x over previous
//
#include <hip/hip_runtime.h>

#define DEV __device__ __forceinline__

typedef unsigned short u16;
typedef __attribute__((ext_vector_type(8))) short bf16x8;
typedef __attribute__((ext_vector_type(4))) float f32x4;
typedef __attribute__((ext_vector_type(4))) unsigned int u32x4;

// round-to-nearest-even f32 -> bf16
DEV u16 f2bf(float f) {
  union { float f; unsigned u; } un; un.f = f;
  unsigned r = un.u + 0x7fffu + ((un.u >> 16) & 1u);
  return (u16)(r >> 16);
}

DEV void gload16(const void* g, void* l) {
  __builtin_amdgcn_global_load_lds((const __attribute__((address_space(1))) void*)g,
                                   (__attribute__((address_space(3))) void*)l, 16, 0, 0);
}

template <int N>
DEV void vm_wait() { asm volatile("s_waitcnt vmcnt(%0)" :: "n"(N) : "memory"); }

DEV float blk_sum(float v, volatile float* sb) {
#pragma unroll
  for (int o = 32; o; o >>= 1) v += __shfl_xor(v, o);
  __syncthreads();
  if ((threadIdx.x & 63) == 0) sb[threadIdx.x >> 6] = v;
  __syncthreads();
  return sb[0] + sb[1] + sb[2] + sb[3];
}

// ---------------- LayerNorm (row = 768) -> bf16 ----------------
__global__ __launch_bounds__(256) void ln_kernel(const float* __restrict__ x,
                                                 const float* __restrict__ g,
                                                 const float* __restrict__ b,
                                                 u16* __restrict__ y) {
  __shared__ float sb[4];
  const size_t row = blockIdx.x;
  const float* xr = x + row * 768;
  const int t = threadIdx.x;
  float v0 = xr[t], v1 = xr[t + 256], v2 = xr[t + 512];
  float mean = blk_sum(v0 + v1 + v2, sb) * (1.0f / 768.0f);
  float d0 = v0 - mean, d1 = v1 - mean, d2 = v2 - mean;
  float var = blk_sum(d0 * d0 + d1 * d1 + d2 * d2, sb) * (1.0f / 768.0f);
  float inv = rsqrtf(var + 1e-5f);
  u16* yr = y + row * 768;
  yr[t]       = f2bf(d0 * inv * g[t]       + b[t]);
  yr[t + 256] = f2bf(d1 * inv * g[t + 256] + b[t + 256]);
  yr[t + 512] = f2bf(d2 * inv * g[t + 512] + b[t + 512]);
}

// ---------------- weight transpose+convert: in[K][N] f32 -> out[N][K] bf16 ----------------
__global__ __launch_bounds__(256) void wt_transpose(const float* __restrict__ in,
                                                    u16* __restrict__ out, int K, int N) {
  __shared__ float tile[32][33];
  const int tx = threadIdx.x & 31, ty = threadIdx.x >> 5;
  const int n0 = blockIdx.x * 32, k0 = blockIdx.y * 32;
#pragma unroll
  for (int i = 0; i < 4; i++)
    tile[ty + 8 * i][tx] = in[(size_t)(k0 + ty + 8 * i) * N + n0 + tx];
  __syncthreads();
#pragma unroll
  for (int i = 0; i < 4; i++)
    out[(size_t)(n0 + ty + 8 * i) * K + k0 + tx] = f2bf(tile[tx][ty + 8 * i]);
}

// ---------------- V transpose: qkv v-slice [b,s,h,d] -> vT [(b*12+h)*64+d][1024] ----------------
__global__ __launch_bounds__(256) void v_transpose(const u16* __restrict__ qkv,
                                                   u16* __restrict__ vT) {
  __shared__ u16 tile[32][33];
  const int tx = threadIdx.x & 31, ty = threadIdx.x >> 5;
  const int z = blockIdx.z, b = z / 12, h = z % 12;
  const int s0 = blockIdx.x * 32, d0 = blockIdx.y * 32;
#pragma unroll
  for (int i = 0; i < 4; i++)
    tile[ty + 8 * i][tx] =
        qkv[(size_t)(b * 1024 + s0 + ty + 8 * i) * 2304 + 1536 + h * 64 + d0 + tx];
  __syncthreads();
#pragma unroll
  for (int i = 0; i < 4; i++)
    vT[(size_t)(z * 64 + d0 + ty + 8 * i) * 1024 + s0 + tx] = tile[tx][ty + 8 * i];
}

// ---------------- fused poly-norm attention ----------------
// Grid: (32 q-tiles, 24 b*h). Block: 512 thr = 8 waves.
// Wave w computes scores[0..31][w*128 .. w*128+127] in regs (QK^T), block does the
// Newton poly solve with shfl + LDS cross-wave partials, writes bf16 weights into a
// swizzled 64KB LDS tile, then PV: wave (m=w>>2, nf=w&3) computes O[m*16+16][nf*16+16].
__global__ __launch_bounds__(512) void fused_attn(const u16* __restrict__ qkv,
                                                  const u16* __restrict__ vT,
                                                  u16* __restrict__ attn) {
  __shared__ __align__(16) u16 wlds[32 * 1024];  // 64KB, XOR-swizzled
  __shared__ float sp2[32][8], sp3[32][8];
  __shared__ float cl[32];

  const int tid = threadIdx.x;
  const int w = tid >> 6, l = tid & 63;
  const int g = l >> 4, lr = l & 15;
  const int bh = blockIdx.y, b = bh / 12, h = bh % 12;
  const int q0 = blockIdx.x * 32;

  // ---- QK^T (q is pre-scaled by 1/8 in the QKV GEMM) ----
  const u16* qrow = qkv + (size_t)(b * 1024 + q0 + lr) * 2304 + h * 64;
  const u16* krow = qkv + (size_t)(b * 1024 + w * 128 + lr) * 2304 + 768 + h * 64;

  bf16x8 af[2][2];
#pragma unroll
  for (int m = 0; m < 2; m++)
#pragma unroll
    for (int ks = 0; ks < 2; ks++)
      af[m][ks] = *(const bf16x8*)(qrow + m * 16 * 2304 + ks * 32 + g * 8);

  f32x4 acc[2][8];
#pragma unroll
  for (int m = 0; m < 2; m++)
#pragma unroll
    for (int n = 0; n < 8; n++) acc[m][n] = (f32x4){0.f, 0.f, 0.f, 0.f};

#pragma unroll
  for (int n = 0; n < 8; n++) {
    bf16x8 b0 = *(const bf16x8*)(krow + n * 16 * 2304 + g * 8);
    bf16x8 b1 = *(const bf16x8*)(krow + n * 16 * 2304 + 32 + g * 8);
    acc[0][n] = __builtin_amdgcn_mfma_f32_16x16x32_bf16(af[0][0], b0, acc[0][n], 0, 0, 0);
    acc[1][n] = __builtin_amdgcn_mfma_f32_16x16x32_bf16(af[1][0], b0, acc[1][n], 0, 0, 0);
    acc[0][n] = __builtin_amdgcn_mfma_f32_16x16x32_bf16(af[0][1], b1, acc[0][n], 0, 0, 0);
    acc[1][n] = __builtin_amdgcn_mfma_f32_16x16x32_bf16(af[1][1], b1, acc[1][n], 0, 0, 0);
  }
  // lane holds scores for rows m*16 + g*4 + r, cols w*128 + n*16 + lr

  // ---- row max -> c0 = -max - 1 ----
  float m8[2][4];
#pragma unroll
  for (int m = 0; m < 2; m++)
#pragma unroll
    for (int r = 0; r < 4; r++) {
      float v = acc[m][0][r];
#pragma unroll
      for (int n = 1; n < 8; n++) v = fmaxf(v, acc[m][n][r]);
      m8[m][r] = v;
    }
#pragma unroll
  for (int o = 1; o < 16; o <<= 1)
#pragma unroll
    for (int m = 0; m < 2; m++)
#pragma unroll
      for (int r = 0; r < 4; r++) m8[m][r] = fmaxf(m8[m][r], __shfl_xor(m8[m][r], o));
#pragma unroll
  for (int j = 0; j < 8; j++)
    if (lr == j) sp2[(j >> 2) * 16 + g * 4 + (j & 3)][w] = m8[j >> 2][j & 3];
  __syncthreads();
  if (tid < 32) {
    float v = sp2[tid][0];
#pragma unroll
    for (int j = 1; j < 8; j++) v = fmaxf(v, sp2[tid][j]);
    cl[tid] = -v - 1.0f;
  }
  __syncthreads();

  float c[2][4];
#pragma unroll
  for (int m = 0; m < 2; m++)
#pragma unroll
    for (int r = 0; r < 4; r++) c[m][r] = cl[m * 16 + g * 4 + r];

  // ---- 6 Newton iterations ----
#pragma unroll 1
  for (int it = 0; it < 6; it++) {
    float s2[2][4], s3[2][4];
#pragma unroll
    for (int m = 0; m < 2; m++)
#pragma unroll
      for (int r = 0; r < 4; r++) { s2[m][r] = 0.f; s3[m][r] = 0.f; }
#pragma unroll
    for (int m = 0; m < 2; m++)
#pragma unroll
      for (int n = 0; n < 8; n++)
#pragma unroll
        for (int r = 0; r < 4; r++) {
          float rr = __builtin_amdgcn_rcpf(-acc[m][n][r] - c[m][r]);
          float r2 = rr * rr;
          s2[m][r] += r2;
          s3[m][r] = fmaf(r2, rr, s3[m][r]);
        }
#pragma unroll
    for (int o = 1; o < 16; o <<= 1)
#pragma unroll
      for (int m = 0; m < 2; m++)
#pragma unroll
        for (int r = 0; r < 4; r++) {
          s2[m][r] += __shfl_xor(s2[m][r], o);
          s3[m][r] += __shfl_xor(s3[m][r], o);
        }
#pragma unroll
    for (int j = 0; j < 8; j++)
      if (lr == j) {
        sp2[(j >> 2) * 16 + g * 4 + (j & 3)][w] = s2[j >> 2][j & 3];
        sp3[(j >> 2) * 16 + g * 4 + (j & 3)][w] = s3[j >> 2][j & 3];
      }
    __syncthreads();
    if (tid < 32) {
      float S2 = 0.f, S3 = 0.f;
#pragma unroll
      for (int j = 0; j < 8; j++) { S2 += sp2[tid][j]; S3 += sp3[tid][j]; }
      cl[tid] -= (S2 - 1.0f) * __builtin_amdgcn_rcpf(2.0f * S3 + 1e-8f);
    }
    __syncthreads();
#pragma unroll
    for (int m = 0; m < 2; m++)
#pragma unroll
      for (int r = 0; r < 4; r++) c[m][r] = cl[m * 16 + g * 4 + r];
  }

  // ---- weights = base^-2 -> bf16 -> swizzled LDS ----
#pragma unroll
  for (int m = 0; m < 2; m++)
#pragma unroll
    for (int n = 0; n < 8; n++)
#pragma unroll
      for (int r = 0; r < 4; r++) {
        float rr = __builtin_amdgcn_rcpf(-acc[m][n][r] - c[m][r]);
        int row = m * 16 + g * 4 + r;
        int col = w * 128 + n * 16 + lr;
        unsigned off = (unsigned)(row * 2048 + col * 2);
        off ^= (unsigned)(row & 7) << 4;
        *(u16*)((char*)wlds + off) = f2bf(rr * rr);
      }
  __syncthreads();

  // ---- PV: wave (m, nf) computes O rows m*16.., cols nf*16.. over K=1024 ----
  const int pm = w >> 2, nf = w & 3;
  const u16* vrow = vT + (size_t)(bh * 64 + nf * 16 + lr) * 1024;
  const int arow = pm * 16 + lr;
  const unsigned swz = (unsigned)(arow & 7) << 4;
  const unsigned abase = (unsigned)(arow * 2048);
  f32x4 oacc = (f32x4){0.f, 0.f, 0.f, 0.f};
#pragma unroll
  for (int ks = 0; ks < 32; ks++) {
    // full-address XOR: must match the write-side involution bit-for-bit
    bf16x8 afr = *(const bf16x8*)((const char*)wlds +
                                  ((abase + (unsigned)(ks * 64 + g * 16)) ^ swz));
    bf16x8 bfr = *(const bf16x8*)(vrow + ks * 32 + g * 8);
    oacc = __builtin_amdgcn_mfma_f32_16x16x32_bf16(afr, bfr, oacc, 0, 0, 0);
  }
  u16* orow = attn + (size_t)(b * 1024 + q0 + pm * 16 + g * 4) * 768 + h * 64 + nf * 16 + lr;
#pragma unroll
  for (int r = 0; r < 4; r++) orow[(size_t)r * 768] = f2bf(oacc[r]);
}

// ---------------- split-K reduce: out = p0+p1+p2+p3 + bias + res ----------------
__global__ __launch_bounds__(256) void splitk_reduce(const float* __restrict__ p,
                                                     const float* __restrict__ bias,
                                                     const float* __restrict__ res,
                                                     float* __restrict__ out) {
  const size_t S = 2048ull * 768;
  size_t i = ((size_t)blockIdx.x * 256 + threadIdx.x) * 4;
  f32x4 v = *(const f32x4*)&p[i];
  v += *(const f32x4*)&p[i + S];
  v += *(const f32x4*)&p[i + 2 * S];
  v += *(const f32x4*)&p[i + 3 * S];
  int col = (int)(i % 768);
  v += *(const f32x4*)&bias[col];
  v += *(const f32x4*)&res[i];
  *(f32x4*)&out[i] = v;
}

// ---------------- pipelined MFMA GEMM: C = A[M][K] * Bt[N][K]^T ----------------
// BM in {64,128}. BM=128: 4 waves as 2x2, BN = 2*WN*16. BM=64: 4 waves as 1x4, BN = 4*WN*16.
// 3-buffer LDS, 2-deep global_load_lds prefetch, counted vmcnt, raw s_barrier (no drain).
// EPI: 0=fused QKV (bias-select + q scale, bf16 out), 1=f32 plain, 2=bf16 plain,
//      3=f32 + bias + residual, 4=GELU(acc+bias) bf16
template <int BM, int WN, int EPI>
__global__ __launch_bounds__(256) void gemm_bt(
    const u16* __restrict__ A, int lda, long long sAb, long long sAh,
    const u16* __restrict__ B0, const u16* __restrict__ B1, const u16* __restrict__ B2,
    int ldb, long long sBb, long long sBh,
    void* __restrict__ Cv, int ldc, long long sCb, long long sCh,
    const float* __restrict__ bias0, const float* __restrict__ bias1,
    const float* __restrict__ bias2, const float* __restrict__ res, int K) {
  constexpr int WCOL = (BM == 128) ? 2 : 4;
  constexpr int BN = WCOL * WN * 16;
  constexpr int NA = BM / 64;
  constexpr int NB = BN / 64;
  constexpr int LT = NA + NB;
  __shared__ __align__(16) u16 lds_a[3][BM * 32];
  __shared__ __align__(16) u16 lds_b[3][BN * 32];

  const int zb = blockIdx.z / 12, zh = blockIdx.z % 12;
  A += zb * sAb + zh * sAh;

  const int colbase = blockIdx.y * BN;
  const u16* B = B0;
  const float* bias = bias0;
  int biasoff = 0;
  float qscale = 1.0f;
  if (EPI == 0) {
    int sel = colbase / 768;
    B = (sel == 0) ? B0 : ((sel == 1) ? B1 : B2);
    bias = (sel == 0) ? bias0 : ((sel == 1) ? bias1 : bias2);
    biasoff = sel * 768;
    qscale = (sel == 0) ? 0.125f : 1.0f;  // 1/sqrt(64) on q only
  }
  B += zb * sBb + zh * sBh;

  const int tid = threadIdx.x;
  const size_t ldab = (size_t)lda * 2, ldbb = (size_t)ldb * 2;
  const char* Abase = (const char*)(A + (size_t)blockIdx.x * BM * lda);
  const char* Bbase = (const char*)(B + (size_t)(colbase - biasoff) * ldb);

  const char* ap[NA];
  const char* bp[NB];
#pragma unroll
  for (int j = 0; j < NA; j++) {
    int lin = (j * 256 + tid) * 16;
    ap[j] = Abase + (size_t)(lin >> 6) * ldab + (lin & 63);
  }
#pragma unroll
  for (int j = 0; j < NB; j++) {
    int lin = (j * 256 + tid) * 16;
    bp[j] = Bbase + (size_t)(lin >> 6) * ldbb + (lin & 63);
  }

  auto stage = [&](int buf) {
#pragma unroll
    for (int j = 0; j < NA; j++) {
      gload16(ap[j], (char*)&lds_a[buf][0] + (j * 256 + tid) * 16);
      ap[j] += 64;
    }
#pragma unroll
    for (int j = 0; j < NB; j++) {
      gload16(bp[j], (char*)&lds_b[buf][0] + (j * 256 + tid) * 16);
      bp[j] += 64;
    }
  };

  f32x4 acc[4][WN];
#pragma unroll
  for (int m = 0; m < 4; m++)
#pragma unroll
    for (int n = 0; n < WN; n++) acc[m][n] = (f32x4){0.f, 0.f, 0.f, 0.f};

  const int w = tid >> 6, l = tid & 63;
  const int wm = (BM == 128) ? (w >> 1) : 0;
  const int wn = (BM == 128) ? (w & 1) : w;
  const int lr = l & 15, kg = l >> 4;

  const int nt = K / 32;
  stage(0);
  if (nt > 1) stage(1);

  for (int t = 0; t < nt; ++t) {
    const int buf = t % 3;
    if (t + 2 < nt) {
      stage((t + 2) % 3);
      vm_wait<2 * LT>();
    } else if (t + 1 < nt) {
      vm_wait<LT>();
    } else {
      vm_wait<0>();
    }
    __builtin_amdgcn_sched_barrier(0);
    __builtin_amdgcn_s_barrier();
    __builtin_amdgcn_sched_barrier(0);

    bf16x8 af[4], bfr[WN];
#pragma unroll
    for (int m = 0; m < 4; m++)
      af[m] = *(const bf16x8*)&lds_a[buf][(wm * 64 + m * 16 + lr) * 32 + kg * 8];
#pragma unroll
    for (int n = 0; n < WN; n++)
      bfr[n] = *(const bf16x8*)&lds_b[buf][(wn * WN * 16 + n * 16 + lr) * 32 + kg * 8];
#pragma unroll
    for (int m = 0; m < 4; m++)
#pragma unroll
      for (int n = 0; n < WN; n++)
        acc[m][n] = __builtin_amdgcn_mfma_f32_16x16x32_bf16(af[m], bfr[n], acc[m][n], 0, 0, 0);

    __builtin_amdgcn_sched_barrier(0);
    __builtin_amdgcn_s_barrier();
    __builtin_amdgcn_sched_barrier(0);
  }

  const int row0 = blockIdx.x * BM + ((BM == 128) ? wm * 64 : 0) + kg * 4;
  const int colb = colbase + wn * WN * 16;
  float* Cf = (float*)Cv + (size_t)zb * sCb + (size_t)zh * sCh;
  u16* Cu = (u16*)Cv + (size_t)zb * sCb + (size_t)zh * sCh;
#pragma unroll
  for (int m = 0; m < 4; m++) {
#pragma unroll
    for (int n = 0; n < WN; n++) {
#pragma unroll
      for (int r = 0; r < 4; r++) {
        int row = row0 + m * 16 + r;
        int col = colb + n * 16 + lr;
        size_t idx = (size_t)row * ldc + col;
        float v = acc[m][n][r];
        if (EPI == 0) {
          Cu[idx] = f2bf((v + bias[col - biasoff]) * qscale);
        } else if (EPI == 1) {
          Cf[idx] = v;
        } else if (EPI == 2) {
          Cu[idx] = f2bf(v);
        } else if (EPI == 3) {
          Cf[idx] = v + bias[col] + res[idx];
        } else {  // exact GELU
          v += bias[col];
          Cu[idx] = f2bf(0.5f * v * (1.0f + erff(v * 0.70710678118654752f)));
        }
      }
    }
  }
}

extern "C" void kernel_launch(void* const* d_in, const int* in_sizes, int n_in,
                              void* d_out, int out_size, void* d_ws, size_t ws_size,
                              hipStream_t stream) {
  const float* x     = (const float*)d_in[0];
  const float* ln1_g = (const float*)d_in[1];
  const float* ln1_b = (const float*)d_in[2];
  const float* wq    = (const float*)d_in[3];
  const float* bq    = (const float*)d_in[4];
  const float* wk    = (const float*)d_in[5];
  const float* bk    = (const float*)d_in[6];
  const float* wv    = (const float*)d_in[7];
  const float* bv    = (const float*)d_in[8];
  const float* wo    = (const float*)d_in[9];
  const float* bo    = (const float*)d_in[10];
  const float* ln2_g = (const float*)d_in[11];
  const float* ln2_b = (const float*)d_in[12];
  const float* w1    = (const float*)d_in[13];
  const float* b1    = (const float*)d_in[14];
  const float* w2    = (const float*)d_in[15];
  const float* b2    = (const float*)d_in[16];
  float* out = (float*)d_out;

  char* p = (char*)d_ws;
  auto alloc = [&](size_t n) { char* r = p; p += (n + 255) & ~(size_t)255; return r; };
  u16*   qkv    = (u16*)  alloc(2048ull * 2304 * 2);       // [b*1024+s][2304] q|k|v bf16
  u16*   y1     = (u16*)  alloc(2048ull * 768 * 2);
  u16*   vT     = (u16*)  alloc(24ull * 64 * 1024 * 2);    // [(b*12+h)*64+d][1024]
  u16*   attn   = (u16*)  alloc(2048ull * 768 * 2);
  float* x1     = (float*)alloc(2048ull * 768 * 4);
  u16*   y2     = (u16*)  alloc(2048ull * 768 * 2);
  u16*   hbuf   = (u16*)  alloc(2048ull * 3072 * 2);
  float* pbuf   = (float*)alloc(4ull * 2048 * 768 * 4);    // split-K partials
  u16*   wq_t   = (u16*)  alloc(768ull * 768 * 2);
  u16*   wk_t   = (u16*)  alloc(768ull * 768 * 2);
  u16*   wv_t   = (u16*)  alloc(768ull * 768 * 2);
  u16*   wo_t   = (u16*)  alloc(768ull * 768 * 2);
  u16*   w1_t   = (u16*)  alloc(3072ull * 768 * 2);
  u16*   w2_t   = (u16*)  alloc(768ull * 3072 * 2);
  (void)in_sizes; (void)n_in; (void)out_size; (void)ws_size;

  // weights -> bf16 [N][K]
  wt_transpose<<<dim3(24, 24), 256, 0, stream>>>(wq, wq_t, 768, 768);
  wt_transpose<<<dim3(24, 24), 256, 0, stream>>>(wk, wk_t, 768, 768);
  wt_transpose<<<dim3(24, 24), 256, 0, stream>>>(wv, wv_t, 768, 768);
  wt_transpose<<<dim3(24, 24), 256, 0, stream>>>(wo, wo_t, 768, 768);
  wt_transpose<<<dim3(96, 24), 256, 0, stream>>>(w1, w1_t, 768, 3072);
  wt_transpose<<<dim3(24, 96), 256, 0, stream>>>(w2, w2_t, 3072, 768);

  // LN1
  ln_kernel<<<2048, 256, 0, stream>>>(x, ln1_g, ln1_b, y1);

  // fused QKV projection: [2048,768] x [768,2304] -> qkv bf16 (q scaled by 1/8)
  gemm_bt<128, 4, 0><<<dim3(16, 18, 1), 256, 0, stream>>>(
      y1, 768, 0, 0, wq_t, wk_t, wv_t, 768, 0, 0, qkv, 2304, 0, 0, bq, bk, bv, nullptr, 768);

  // V transpose
  v_transpose<<<dim3(32, 2, 24), 256, 0, stream>>>(qkv, vT);

  // fused poly-norm attention: QK^T + Newton + PV, scores never touch HBM
  fused_attn<<<dim3(32, 24), 512, 0, stream>>>(qkv, vT, attn);

  // x1 = x + attn @ wo + bo
  gemm_bt<64, 2, 3><<<dim3(32, 6, 1), 256, 0, stream>>>(
      attn, 768, 0, 0, wo_t, nullptr, nullptr, 768, 0, 0, x1, 768, 0, 0,
      bo, nullptr, nullptr, x, 768);

  // LN2
  ln_kernel<<<2048, 256, 0, stream>>>(x1, ln2_g, ln2_b, y2);

  // h = gelu(y2 @ w1 + b1)
  gemm_bt<128, 4, 4><<<dim3(16, 24, 1), 256, 0, stream>>>(
      y2, 768, 0, 0, w1_t, nullptr, nullptr, 768, 0, 0, hbuf, 3072, 0, 0,
      b1, nullptr, nullptr, nullptr, 768);

  // MLP2 split-K x4: partials = h[:, z*768:(z+1)*768] @ w2_t[:, z*768:(z+1)*768]^T
  gemm_bt<64, 2, 1><<<dim3(32, 6, 4), 256, 0, stream>>>(
      hbuf, 3072, 0, 768LL, w2_t, nullptr, nullptr, 3072, 0, 768LL,
      pbuf, 768, 0, 1572864LL, nullptr, nullptr, nullptr, nullptr, 768);

  // out = sum(partials) + b2 + x1
  splitk_reduce<<<1536, 256, 0, stream>>>(pbuf, b2, x1, out);
}

// Round 7
// 191.590 us; speedup vs baseline: 1.7755x; 1.0540x over previous
//
#include <hip/hip_runtime.h>

#define DEV __device__ __forceinline__

typedef unsigned short u16;
typedef __attribute__((ext_vector_type(8))) short bf16x8;
typedef __attribute__((ext_vector_type(4))) float f32x4;
typedef __attribute__((ext_vector_type(4))) unsigned int u32x4;

// round-to-nearest-even f32 -> bf16
DEV u16 f2bf(float f) {
  union { float f; unsigned u; } un; un.f = f;
  unsigned r = un.u + 0x7fffu + ((un.u >> 16) & 1u);
  return (u16)(r >> 16);
}

DEV void gload16(const void* g, void* l) {
  __builtin_amdgcn_global_load_lds((const __attribute__((address_space(1))) void*)g,
                                   (__attribute__((address_space(3))) void*)l, 16, 0, 0);
}

template <int N>
DEV void vm_wait() { asm volatile("s_waitcnt vmcnt(%0)" :: "n"(N) : "memory"); }

DEV float blk_sum(float v, volatile float* sb) {
#pragma unroll
  for (int o = 32; o; o >>= 1) v += __shfl_xor(v, o);
  __syncthreads();
  if ((threadIdx.x & 63) == 0) sb[threadIdx.x >> 6] = v;
  __syncthreads();
  return sb[0] + sb[1] + sb[2] + sb[3];
}

// ---------------- LayerNorm (row = 768) -> bf16 ----------------
__global__ __launch_bounds__(256) void ln_kernel(const float* __restrict__ x,
                                                 const float* __restrict__ g,
                                                 const float* __restrict__ b,
                                                 u16* __restrict__ y) {
  __shared__ float sb[4];
  const size_t row = blockIdx.x;
  const float* xr = x + row * 768;
  const int t = threadIdx.x;
  float v0 = xr[t], v1 = xr[t + 256], v2 = xr[t + 512];
  float mean = blk_sum(v0 + v1 + v2, sb) * (1.0f / 768.0f);
  float d0 = v0 - mean, d1 = v1 - mean, d2 = v2 - mean;
  float var = blk_sum(d0 * d0 + d1 * d1 + d2 * d2, sb) * (1.0f / 768.0f);
  float inv = rsqrtf(var + 1e-5f);
  u16* yr = y + row * 768;
  yr[t]       = f2bf(d0 * inv * g[t]       + b[t]);
  yr[t + 256] = f2bf(d1 * inv * g[t + 256] + b[t + 256]);
  yr[t + 512] = f2bf(d2 * inv * g[t + 512] + b[t + 512]);
}

// ---------------- weight transpose+convert: in[K][N] f32 -> out[N][K] bf16 ----------------
__global__ __launch_bounds__(256) void wt_transpose(const float* __restrict__ in,
                                                    u16* __restrict__ out, int K, int N) {
  __shared__ float tile[32][33];
  const int tx = threadIdx.x & 31, ty = threadIdx.x >> 5;
  const int n0 = blockIdx.x * 32, k0 = blockIdx.y * 32;
#pragma unroll
  for (int i = 0; i < 4; i++)
    tile[ty + 8 * i][tx] = in[(size_t)(k0 + ty + 8 * i) * N + n0 + tx];
  __syncthreads();
#pragma unroll
  for (int i = 0; i < 4; i++)
    out[(size_t)(n0 + ty + 8 * i) * K + k0 + tx] = f2bf(tile[tx][ty + 8 * i]);
}

// ---------------- V transpose: qkv v-slice [b,s,h,d] -> vT [(b*12+h)*64+d][1024] ----------------
__global__ __launch_bounds__(256) void v_transpose(const u16* __restrict__ qkv,
                                                   u16* __restrict__ vT) {
  __shared__ u16 tile[32][33];
  const int tx = threadIdx.x & 31, ty = threadIdx.x >> 5;
  const int z = blockIdx.z, b = z / 12, h = z % 12;
  const int s0 = blockIdx.x * 32, d0 = blockIdx.y * 32;
#pragma unroll
  for (int i = 0; i < 4; i++)
    tile[ty + 8 * i][tx] =
        qkv[(size_t)(b * 1024 + s0 + ty + 8 * i) * 2304 + 1536 + h * 64 + d0 + tx];
  __syncthreads();
#pragma unroll
  for (int i = 0; i < 4; i++)
    vT[(size_t)(z * 64 + d0 + ty + 8 * i) * 1024 + s0 + tx] = tile[tx][ty + 8 * i];
}

// ---------------- fused poly-norm attention (16-row q-tiles, R5-proven sync shape) ------
// Grid: (64 q-tiles, 24 b*h). Block: 512 thr = 8 waves.
// Wave w computes scores[0..15][w*128 .. +127] in regs (QK^T). Block does the Newton
// poly solve (shfl within 16-lane groups + LDS cross-wave partials), writes bf16
// weights to a swizzled 32KB LDS tile; ONE barrier; then waves 0..3 each compute
// O[16][w*16..+16] over the full K=1024 and write directly to global (no cross-wave
// combine — same sync structure as the validated 32-row version). Waves 4..7 exit.
// LDS ~34KB -> 4 blocks/CU for barrier/serial-phase overlap.
__global__ __launch_bounds__(512) void fused_attn(const u16* __restrict__ qkv,
                                                  const u16* __restrict__ vT,
                                                  u16* __restrict__ attn) {
  __shared__ __align__(16) u16 wlds[16 * 1024];  // 32KB, XOR-swizzled
  __shared__ float sp2[16][8], sp3[16][8];
  __shared__ float cl[16];

  const int tid = threadIdx.x;
  const int w = tid >> 6, l = tid & 63;
  const int g = l >> 4, lr = l & 15;
  const int bh = blockIdx.y, b = bh / 12, h = bh % 12;
  const int q0 = blockIdx.x * 16;

  // ---- QK^T (q pre-scaled by 1/8 in the QKV GEMM) ----
  const u16* qrow = qkv + (size_t)(b * 1024 + q0 + lr) * 2304 + h * 64;
  const u16* krow = qkv + (size_t)(b * 1024 + w * 128 + lr) * 2304 + 768 + h * 64;

  bf16x8 af[2];
  af[0] = *(const bf16x8*)(qrow + g * 8);
  af[1] = *(const bf16x8*)(qrow + 32 + g * 8);

  f32x4 acc[8];
#pragma unroll
  for (int n = 0; n < 8; n++) acc[n] = (f32x4){0.f, 0.f, 0.f, 0.f};

#pragma unroll
  for (int n = 0; n < 8; n++) {
    bf16x8 b0 = *(const bf16x8*)(krow + n * 16 * 2304 + g * 8);
    bf16x8 b1 = *(const bf16x8*)(krow + n * 16 * 2304 + 32 + g * 8);
    acc[n] = __builtin_amdgcn_mfma_f32_16x16x32_bf16(af[0], b0, acc[n], 0, 0, 0);
    acc[n] = __builtin_amdgcn_mfma_f32_16x16x32_bf16(af[1], b1, acc[n], 0, 0, 0);
  }
  // lane holds scores for rows g*4 + r (q-local), cols w*128 + n*16 + lr

  // ---- row max -> c0 = -max - 1 ----
  float m4[4];
#pragma unroll
  for (int r = 0; r < 4; r++) {
    float v = acc[0][r];
#pragma unroll
    for (int n = 1; n < 8; n++) v = fmaxf(v, acc[n][r]);
    m4[r] = v;
  }
#pragma unroll
  for (int o = 1; o < 16; o <<= 1)
#pragma unroll
    for (int r = 0; r < 4; r++) m4[r] = fmaxf(m4[r], __shfl_xor(m4[r], o));
#pragma unroll
  for (int j = 0; j < 4; j++)
    if (lr == j) sp2[g * 4 + j][w] = m4[j];
  __syncthreads();
  if (tid < 16) {
    float v = sp2[tid][0];
#pragma unroll
    for (int j = 1; j < 8; j++) v = fmaxf(v, sp2[tid][j]);
    cl[tid] = -v - 1.0f;
  }
  __syncthreads();

  float c[4];
#pragma unroll
  for (int r = 0; r < 4; r++) c[r] = cl[g * 4 + r];

  // ---- 6 Newton iterations ----
#pragma unroll 1
  for (int it = 0; it < 6; it++) {
    float s2[4], s3[4];
#pragma unroll
    for (int r = 0; r < 4; r++) { s2[r] = 0.f; s3[r] = 0.f; }
#pragma unroll
    for (int n = 0; n < 8; n++)
#pragma unroll
      for (int r = 0; r < 4; r++) {
        float rr = __builtin_amdgcn_rcpf(-acc[n][r] - c[r]);
        float r2 = rr * rr;
        s2[r] += r2;
        s3[r] = fmaf(r2, rr, s3[r]);
      }
#pragma unroll
    for (int o = 1; o < 16; o <<= 1)
#pragma unroll
      for (int r = 0; r < 4; r++) {
        s2[r] += __shfl_xor(s2[r], o);
        s3[r] += __shfl_xor(s3[r], o);
      }
#pragma unroll
    for (int j = 0; j < 4; j++)
      if (lr == j) {
        sp2[g * 4 + j][w] = s2[j];
        sp3[g * 4 + j][w] = s3[j];
      }
    __syncthreads();
    if (tid < 16) {
      float S2 = 0.f, S3 = 0.f;
#pragma unroll
      for (int j = 0; j < 8; j++) { S2 += sp2[tid][j]; S3 += sp3[tid][j]; }
      cl[tid] -= (S2 - 1.0f) * __builtin_amdgcn_rcpf(2.0f * S3 + 1e-8f);
    }
    __syncthreads();
#pragma unroll
    for (int r = 0; r < 4; r++) c[r] = cl[g * 4 + r];
  }

  // ---- weights = base^-2 -> bf16 -> swizzled LDS ----
#pragma unroll
  for (int n = 0; n < 8; n++)
#pragma unroll
    for (int r = 0; r < 4; r++) {
      float rr = __builtin_amdgcn_rcpf(-acc[n][r] - c[r]);
      int row = g * 4 + r;
      int col = w * 128 + n * 16 + lr;
      unsigned off = (unsigned)(row * 2048 + col * 2);
      off ^= (unsigned)(row & 7) << 4;
      *(u16*)((char*)wlds + off) = f2bf(rr * rr);
    }
  __syncthreads();

  // ---- PV: waves 0..3 only — wave w: O[16][w*16..+16] over full K=1024 ----
  if (w < 4) {
    const int nf = w;
    const u16* vrow = vT + (size_t)(bh * 64 + nf * 16 + lr) * 1024;
    const unsigned swz = (unsigned)(lr & 7) << 4;
    const unsigned abase = (unsigned)(lr * 2048);
    f32x4 oacc = (f32x4){0.f, 0.f, 0.f, 0.f};
#pragma unroll
    for (int ks = 0; ks < 32; ks++) {
      // full-address XOR matching the write-side involution
      bf16x8 afr = *(const bf16x8*)((const char*)wlds +
                                    ((abase + (unsigned)(ks * 64 + g * 16)) ^ swz));
      bf16x8 bfr = *(const bf16x8*)(vrow + ks * 32 + g * 8);
      oacc = __builtin_amdgcn_mfma_f32_16x16x32_bf16(afr, bfr, oacc, 0, 0, 0);
    }
    u16* orow = attn + (size_t)(b * 1024 + q0 + g * 4) * 768 + h * 64 + nf * 16 + lr;
#pragma unroll
    for (int r = 0; r < 4; r++) orow[(size_t)r * 768] = f2bf(oacc[r]);
  }
}

// ---------------- split-K reduce: out = p0+p1+p2+p3 + bias + res ----------------
__global__ __launch_bounds__(256) void splitk_reduce(const float* __restrict__ p,
                                                     const float* __restrict__ bias,
                                                     const float* __restrict__ res,
                                                     float* __restrict__ out) {
  const size_t S = 2048ull * 768;
  size_t i = ((size_t)blockIdx.x * 256 + threadIdx.x) * 4;
  f32x4 v = *(const f32x4*)&p[i];
  v += *(const f32x4*)&p[i + S];
  v += *(const f32x4*)&p[i + 2 * S];
  v += *(const f32x4*)&p[i + 3 * S];
  int col = (int)(i % 768);
  v += *(const f32x4*)&bias[col];
  v += *(const f32x4*)&res[i];
  *(f32x4*)&out[i] = v;
}

// ---------------- pipelined MFMA GEMM: C = A[M][K] * Bt[N][K]^T ----------------
// BM in {64,128}. BM=128: 4 waves as 2x2, BN = 2*WN*16. BM=64: 4 waves as 1x4, BN = 4*WN*16.
// 3-buffer LDS, 2-deep global_load_lds prefetch, counted vmcnt, raw s_barrier (no drain).
// EPI: 0=fused QKV (bias-select + q scale, bf16 out), 1=f32 plain, 2=bf16 plain,
//      3=f32 + bias + residual, 4=GELU(acc+bias) bf16
template <int BM, int WN, int EPI>
__global__ __launch_bounds__(256) void gemm_bt(
    const u16* __restrict__ A, int lda, long long sAb, long long sAh,
    const u16* __restrict__ B0, const u16* __restrict__ B1, const u16* __restrict__ B2,
    int ldb, long long sBb, long long sBh,
    void* __restrict__ Cv, int ldc, long long sCb, long long sCh,
    const float* __restrict__ bias0, const float* __restrict__ bias1,
    const float* __restrict__ bias2, const float* __restrict__ res, int K) {
  constexpr int WCOL = (BM == 128) ? 2 : 4;
  constexpr int BN = WCOL * WN * 16;
  constexpr int NA = BM / 64;
  constexpr int NB = BN / 64;
  constexpr int LT = NA + NB;
  __shared__ __align__(16) u16 lds_a[3][BM * 32];
  __shared__ __align__(16) u16 lds_b[3][BN * 32];

  const int zb = blockIdx.z / 12, zh = blockIdx.z % 12;
  A += zb * sAb + zh * sAh;

  const int colbase = blockIdx.y * BN;
  const u16* B = B0;
  const float* bias = bias0;
  int biasoff = 0;
  float qscale = 1.0f;
  if (EPI == 0) {
    int sel = colbase / 768;
    B = (sel == 0) ? B0 : ((sel == 1) ? B1 : B2);
    bias = (sel == 0) ? bias0 : ((sel == 1) ? bias1 : bias2);
    biasoff = sel * 768;
    qscale = (sel == 0) ? 0.125f : 1.0f;  // 1/sqrt(64) on q only
  }
  B += zb * sBb + zh * sBh;

  const int tid = threadIdx.x;
  const size_t ldab = (size_t)lda * 2, ldbb = (size_t)ldb * 2;
  const char* Abase = (const char*)(A + (size_t)blockIdx.x * BM * lda);
  const char* Bbase = (const char*)(B + (size_t)(colbase - biasoff) * ldb);

  const char* ap[NA];
  const char* bp[NB];
#pragma unroll
  for (int j = 0; j < NA; j++) {
    int lin = (j * 256 + tid) * 16;
    ap[j] = Abase + (size_t)(lin >> 6) * ldab + (lin & 63);
  }
#pragma unroll
  for (int j = 0; j < NB; j++) {
    int lin = (j * 256 + tid) * 16;
    bp[j] = Bbase + (size_t)(lin >> 6) * ldbb + (lin & 63);
  }

  auto stage = [&](int buf) {
#pragma unroll
    for (int j = 0; j < NA; j++) {
      gload16(ap[j], (char*)&lds_a[buf][0] + (j * 256 + tid) * 16);
      ap[j] += 64;
    }
#pragma unroll
    for (int j = 0; j < NB; j++) {
      gload16(bp[j], (char*)&lds_b[buf][0] + (j * 256 + tid) * 16);
      bp[j] += 64;
    }
  };

  f32x4 acc[4][WN];
#pragma unroll
  for (int m = 0; m < 4; m++)
#pragma unroll
    for (int n = 0; n < WN; n++) acc[m][n] = (f32x4){0.f, 0.f, 0.f, 0.f};

  const int w = tid >> 6, l = tid & 63;
  const int wm = (BM == 128) ? (w >> 1) : 0;
  const int wn = (BM == 128) ? (w & 1) : w;
  const int lr = l & 15, kg = l >> 4;

  const int nt = K / 32;
  stage(0);
  if (nt > 1) stage(1);

  for (int t = 0; t < nt; ++t) {
    const int buf = t % 3;
    if (t + 2 < nt) {
      stage((t + 2) % 3);
      vm_wait<2 * LT>();
    } else if (t + 1 < nt) {
      vm_wait<LT>();
    } else {
      vm_wait<0>();
    }
    __builtin_amdgcn_sched_barrier(0);
    __builtin_amdgcn_s_barrier();
    __builtin_amdgcn_sched_barrier(0);

    bf16x8 af[4], bfr[WN];
#pragma unroll
    for (int m = 0; m < 4; m++)
      af[m] = *(const bf16x8*)&lds_a[buf][(wm * 64 + m * 16 + lr) * 32 + kg * 8];
#pragma unroll
    for (int n = 0; n < WN; n++)
      bfr[n] = *(const bf16x8*)&lds_b[buf][(wn * WN * 16 + n * 16 + lr) * 32 + kg * 8];
#pragma unroll
    for (int m = 0; m < 4; m++)
#pragma unroll
      for (int n = 0; n < WN; n++)
        acc[m][n] = __builtin_amdgcn_mfma_f32_16x16x32_bf16(af[m], bfr[n], acc[m][n], 0, 0, 0);

    __builtin_amdgcn_sched_barrier(0);
    __builtin_amdgcn_s_barrier();
    __builtin_amdgcn_sched_barrier(0);
  }

  const int row0 = blockIdx.x * BM + ((BM == 128) ? wm * 64 : 0) + kg * 4;
  const int colb = colbase + wn * WN * 16;
  float* Cf = (float*)Cv + (size_t)zb * sCb + (size_t)zh * sCh;
  u16* Cu = (u16*)Cv + (size_t)zb * sCb + (size_t)zh * sCh;
#pragma unroll
  for (int m = 0; m < 4; m++) {
#pragma unroll
    for (int n = 0; n < WN; n++) {
#pragma unroll
      for (int r = 0; r < 4; r++) {
        int row = row0 + m * 16 + r;
        int col = colb + n * 16 + lr;
        size_t idx = (size_t)row * ldc + col;
        float v = acc[m][n][r];
        if (EPI == 0) {
          Cu[idx] = f2bf((v + bias[col - biasoff]) * qscale);
        } else if (EPI == 1) {
          Cf[idx] = v;
        } else if (EPI == 2) {
          Cu[idx] = f2bf(v);
        } else if (EPI == 3) {
          Cf[idx] = v + bias[col] + res[idx];
        } else {  // exact GELU
          v += bias[col];
          Cu[idx] = f2bf(0.5f * v * (1.0f + erff(v * 0.70710678118654752f)));
        }
      }
    }
  }
}

extern "C" void kernel_launch(void* const* d_in, const int* in_sizes, int n_in,
                              void* d_out, int out_size, void* d_ws, size_t ws_size,
                              hipStream_t stream) {
  const float* x     = (const float*)d_in[0];
  const float* ln1_g = (const float*)d_in[1];
  const float* ln1_b = (const float*)d_in[2];
  const float* wq    = (const float*)d_in[3];
  const float* bq    = (const float*)d_in[4];
  const float* wk    = (const float*)d_in[5];
  const float* bk    = (const float*)d_in[6];
  const float* wv    = (const float*)d_in[7];
  const float* bv    = (const float*)d_in[8];
  const float* wo    = (const float*)d_in[9];
  const float* bo    = (const float*)d_in[10];
  const float* ln2_g = (const float*)d_in[11];
  const float* ln2_b = (const float*)d_in[12];
  const float* w1    = (const float*)d_in[13];
  const float* b1    = (const float*)d_in[14];
  const float* w2    = (const float*)d_in[15];
  const float* b2    = (const float*)d_in[16];
  float* out = (float*)d_out;

  char* p = (char*)d_ws;
  auto alloc = [&](size_t n) { char* r = p; p += (n + 255) & ~(size_t)255; return r; };
  u16*   qkv    = (u16*)  alloc(2048ull * 2304 * 2);       // [b*1024+s][2304] q|k|v bf16
  u16*   y1     = (u16*)  alloc(2048ull * 768 * 2);
  u16*   vT     = (u16*)  alloc(24ull * 64 * 1024 * 2);    // [(b*12+h)*64+d][1024]
  u16*   attn   = (u16*)  alloc(2048ull * 768 * 2);
  float* x1     = (float*)alloc(2048ull * 768 * 4);
  u16*   y2     = (u16*)  alloc(2048ull * 768 * 2);
  u16*   hbuf   = (u16*)  alloc(2048ull * 3072 * 2);
  float* pbuf   = (float*)alloc(4ull * 2048 * 768 * 4);    // split-K partials
  u16*   wq_t   = (u16*)  alloc(768ull * 768 * 2);
  u16*   wk_t   = (u16*)  alloc(768ull * 768 * 2);
  u16*   wv_t   = (u16*)  alloc(768ull * 768 * 2);
  u16*   wo_t   = (u16*)  alloc(768ull * 768 * 2);
  u16*   w1_t   = (u16*)  alloc(3072ull * 768 * 2);
  u16*   w2_t   = (u16*)  alloc(768ull * 3072 * 2);
  (void)in_sizes; (void)n_in; (void)out_size; (void)ws_size;

  // weights -> bf16 [N][K]
  wt_transpose<<<dim3(24, 24), 256, 0, stream>>>(wq, wq_t, 768, 768);
  wt_transpose<<<dim3(24, 24), 256, 0, stream>>>(wk, wk_t, 768, 768);
  wt_transpose<<<dim3(24, 24), 256, 0, stream>>>(wv, wv_t, 768, 768);
  wt_transpose<<<dim3(24, 24), 256, 0, stream>>>(wo, wo_t, 768, 768);
  wt_transpose<<<dim3(96, 24), 256, 0, stream>>>(w1, w1_t, 768, 3072);
  wt_transpose<<<dim3(24, 96), 256, 0, stream>>>(w2, w2_t, 3072, 768);

  // LN1
  ln_kernel<<<2048, 256, 0, stream>>>(x, ln1_g, ln1_b, y1);

  // fused QKV projection: [2048,768] x [768,2304] -> qkv bf16 (q scaled by 1/8)
  gemm_bt<128, 4, 0><<<dim3(16, 18, 1), 256, 0, stream>>>(
      y1, 768, 0, 0, wq_t, wk_t, wv_t, 768, 0, 0, qkv, 2304, 0, 0, bq, bk, bv, nullptr, 768);

  // V transpose
  v_transpose<<<dim3(32, 2, 24), 256, 0, stream>>>(qkv, vT);

  // fused poly-norm attention: QK^T + Newton + PV, scores never touch HBM
  fused_attn<<<dim3(64, 24), 512, 0, stream>>>(qkv, vT, attn);

  // x1 = x + attn @ wo + bo
  gemm_bt<64, 2, 3><<<dim3(32, 6, 1), 256, 0, stream>>>(
      attn, 768, 0, 0, wo_t, nullptr, nullptr, 768, 0, 0, x1, 768, 0, 0,
      bo, nullptr, nullptr, x, 768);

  // LN2
  ln_kernel<<<2048, 256, 0, stream>>>(x1, ln2_g, ln2_b, y2);

  // h = gelu(y2 @ w1 + b1)
  gemm_bt<128, 4, 4><<<dim3(16, 24, 1), 256, 0, stream>>>(
      y2, 768, 0, 0, w1_t, nullptr, nullptr, 768, 0, 0, hbuf, 3072, 0, 0,
      b1, nullptr, nullptr, nullptr, 768);

  // MLP2 split-K x4: partials = h[:, z*768:(z+1)*768] @ w2_t[:, z*768:(z+1)*768]^T
  gemm_bt<64, 2, 1><<<dim3(32, 6, 4), 256, 0, stream>>>(
      hbuf, 3072, 0, 768LL, w2_t, nullptr, nullptr, 3072, 0, 768LL,
      pbuf, 768, 0, 1572864LL, nullptr, nullptr, nullptr, nullptr, 768);

  // out = sum(partials) + b2 + x1
  splitk_reduce<<<1536, 256, 0, stream>>>(pbuf, b2, x1, out);
}

// Round 8
// 182.722 us; speedup vs baseline: 1.8617x; 1.0485x over previous
//
#include <hip/hip_runtime.h>

#define DEV __device__ __forceinline__

typedef unsigned short u16;
typedef __attribute__((ext_vector_type(8))) short bf16x8;
typedef __attribute__((ext_vector_type(4))) float f32x4;
typedef __attribute__((ext_vector_type(4))) unsigned int u32x4;

// round-to-nearest-even f32 -> bf16
DEV u16 f2bf(float f) {
  union { float f; unsigned u; } un; un.f = f;
  unsigned r = un.u + 0x7fffu + ((un.u >> 16) & 1u);
  return (u16)(r >> 16);
}

DEV void gload16(const void* g, void* l) {
  __builtin_amdgcn_global_load_lds((const __attribute__((address_space(1))) void*)g,
                                   (__attribute__((address_space(3))) void*)l, 16, 0, 0);
}

template <int N>
DEV void vm_wait() { asm volatile("s_waitcnt vmcnt(%0)" :: "n"(N) : "memory"); }

DEV float blk_sum(float v, volatile float* sb) {
#pragma unroll
  for (int o = 32; o; o >>= 1) v += __shfl_xor(v, o);
  __syncthreads();
  if ((threadIdx.x & 63) == 0) sb[threadIdx.x >> 6] = v;
  __syncthreads();
  return sb[0] + sb[1] + sb[2] + sb[3];
}

// ---------------- LayerNorm (row = 768) -> bf16 ----------------
__global__ __launch_bounds__(256) void ln_kernel(const float* __restrict__ x,
                                                 const float* __restrict__ g,
                                                 const float* __restrict__ b,
                                                 u16* __restrict__ y) {
  __shared__ float sb[4];
  const size_t row = blockIdx.x;
  const float* xr = x + row * 768;
  const int t = threadIdx.x;
  float v0 = xr[t], v1 = xr[t + 256], v2 = xr[t + 512];
  float mean = blk_sum(v0 + v1 + v2, sb) * (1.0f / 768.0f);
  float d0 = v0 - mean, d1 = v1 - mean, d2 = v2 - mean;
  float var = blk_sum(d0 * d0 + d1 * d1 + d2 * d2, sb) * (1.0f / 768.0f);
  float inv = rsqrtf(var + 1e-5f);
  u16* yr = y + row * 768;
  yr[t]       = f2bf(d0 * inv * g[t]       + b[t]);
  yr[t + 256] = f2bf(d1 * inv * g[t + 256] + b[t + 256]);
  yr[t + 512] = f2bf(d2 * inv * g[t + 512] + b[t + 512]);
}

// ---------------- weight transpose+convert: in[K][N] f32 -> out[N][K] bf16 ----------------
__global__ __launch_bounds__(256) void wt_transpose(const float* __restrict__ in,
                                                    u16* __restrict__ out, int K, int N) {
  __shared__ float tile[32][33];
  const int tx = threadIdx.x & 31, ty = threadIdx.x >> 5;
  const int n0 = blockIdx.x * 32, k0 = blockIdx.y * 32;
#pragma unroll
  for (int i = 0; i < 4; i++)
    tile[ty + 8 * i][tx] = in[(size_t)(k0 + ty + 8 * i) * N + n0 + tx];
  __syncthreads();
#pragma unroll
  for (int i = 0; i < 4; i++)
    out[(size_t)(n0 + ty + 8 * i) * K + k0 + tx] = f2bf(tile[tx][ty + 8 * i]);
}

// ---------------- V transpose: qkv v-slice [b,s,h,d] -> vT [(b*12+h)*64+d][1024] ----------------
__global__ __launch_bounds__(256) void v_transpose(const u16* __restrict__ qkv,
                                                   u16* __restrict__ vT) {
  __shared__ u16 tile[32][33];
  const int tx = threadIdx.x & 31, ty = threadIdx.x >> 5;
  const int z = blockIdx.z, b = z / 12, h = z % 12;
  const int s0 = blockIdx.x * 32, d0 = blockIdx.y * 32;
#pragma unroll
  for (int i = 0; i < 4; i++)
    tile[ty + 8 * i][tx] =
        qkv[(size_t)(b * 1024 + s0 + ty + 8 * i) * 2304 + 1536 + h * 64 + d0 + tx];
  __syncthreads();
#pragma unroll
  for (int i = 0; i < 4; i++)
    vT[(size_t)(z * 64 + d0 + ty + 8 * i) * 1024 + s0 + tx] = tile[tx][ty + 8 * i];
}

// ---------------- fused poly-norm attention (chunk-redistributed Newton) ----------------
// Grid: (64 q-tiles, 24 b*h). Block: 512 thr = 8 waves. Only 2 barriers total.
// Phase 1: wave w computes scores[0..15][w*128..+127] via MFMA, scatters bf16 scores
//          into the swizzled 32KB LDS tile. BARRIER.
// Phase 2: thread owns row=tid>>5, cols (tid&31)*32..+31 (4x ds_read_b128, same XOR
//          involution). Row max + 6 Newton iterations run entirely in-register with
//          half-wave (32-lane) shfl reduces — zero barriers, zero LDS traffic.
//          Weights written back in place to the same addresses. BARRIER.
// Phase 3: waves 0..3 do PV over full K=1024 (R7-proven shape); waves 4..7 exit.
__global__ __launch_bounds__(512) void fused_attn(const u16* __restrict__ qkv,
                                                  const u16* __restrict__ vT,
                                                  u16* __restrict__ attn) {
  __shared__ __align__(16) u16 wlds[16 * 1024];  // 32KB, XOR-swizzled (scores, then weights)

  const int tid = threadIdx.x;
  const int w = tid >> 6, l = tid & 63;
  const int g = l >> 4, lr = l & 15;
  const int bh = blockIdx.y, b = bh / 12, h = bh % 12;
  const int q0 = blockIdx.x * 16;

  // ---- QK^T (q pre-scaled by 1/8 in the QKV GEMM) ----
  const u16* qrow = qkv + (size_t)(b * 1024 + q0 + lr) * 2304 + h * 64;
  const u16* krow = qkv + (size_t)(b * 1024 + w * 128 + lr) * 2304 + 768 + h * 64;

  bf16x8 af[2];
  af[0] = *(const bf16x8*)(qrow + g * 8);
  af[1] = *(const bf16x8*)(qrow + 32 + g * 8);

  f32x4 acc[8];
#pragma unroll
  for (int n = 0; n < 8; n++) acc[n] = (f32x4){0.f, 0.f, 0.f, 0.f};

#pragma unroll
  for (int n = 0; n < 8; n++) {
    bf16x8 b0 = *(const bf16x8*)(krow + n * 16 * 2304 + g * 8);
    bf16x8 b1 = *(const bf16x8*)(krow + n * 16 * 2304 + 32 + g * 8);
    acc[n] = __builtin_amdgcn_mfma_f32_16x16x32_bf16(af[0], b0, acc[n], 0, 0, 0);
    acc[n] = __builtin_amdgcn_mfma_f32_16x16x32_bf16(af[1], b1, acc[n], 0, 0, 0);
  }
  // lane holds scores for rows g*4 + r (q-local), cols w*128 + n*16 + lr

  // ---- scatter scores (bf16) into swizzled LDS ----
#pragma unroll
  for (int n = 0; n < 8; n++)
#pragma unroll
    for (int r = 0; r < 4; r++) {
      int row = g * 4 + r;
      int col = w * 128 + n * 16 + lr;
      unsigned off = (unsigned)(row * 2048 + col * 2);
      off ^= (unsigned)(row & 7) << 4;
      *(u16*)((char*)wlds + off) = f2bf(acc[n][r]);
    }
  __syncthreads();  // barrier 1

  // ---- chunk read: thread owns row = tid>>5, cols (tid&31)*32 .. +31 ----
  const int crow = tid >> 5, l32 = tid & 31;
  const unsigned cswz = (unsigned)(crow & 7) << 4;
  const unsigned cbase = (unsigned)(crow * 2048 + l32 * 64);
  float xs[32];
#pragma unroll
  for (int j = 0; j < 4; j++) {
    u32x4 raw = *(const u32x4*)((const char*)wlds + ((cbase + j * 16u) ^ cswz));
#pragma unroll
    for (int e = 0; e < 4; e++) {
      union { unsigned u; float f; } lo, hi;
      lo.u = raw[e] << 16;
      hi.u = raw[e] & 0xffff0000u;
      xs[j * 8 + e * 2] = lo.f;
      xs[j * 8 + e * 2 + 1] = hi.f;
    }
  }

  // ---- row max (31 fmax + 5 half-wave shfl) -> c0 = -max - 1 ----
  float mx = xs[0];
#pragma unroll
  for (int i = 1; i < 32; i++) mx = fmaxf(mx, xs[i]);
#pragma unroll
  for (int o = 1; o < 32; o <<= 1) mx = fmaxf(mx, __shfl_xor(mx, o));
  float c = -mx - 1.0f;

  // ---- 6 Newton iterations: fully in-register, zero barriers ----
#pragma unroll 1
  for (int it = 0; it < 6; it++) {
    float s2 = 0.f, s3 = 0.f;
#pragma unroll
    for (int i = 0; i < 32; i++) {
      float rr = __builtin_amdgcn_rcpf(-(xs[i] + c));  // 1/base, base >= 1
      float r2 = rr * rr;
      s2 += r2;
      s3 = fmaf(r2, rr, s3);
    }
#pragma unroll
    for (int o = 1; o < 32; o <<= 1) {
      s2 += __shfl_xor(s2, o);
      s3 += __shfl_xor(s3, o);
    }
    c -= (s2 - 1.0f) * __builtin_amdgcn_rcpf(2.0f * s3 + 1e-8f);
  }

  // ---- weights = base^-2 -> bf16, written back in place (same addresses) ----
#pragma unroll
  for (int j = 0; j < 4; j++) {
    u32x4 outv;
#pragma unroll
    for (int e = 0; e < 4; e++) {
      float r0 = __builtin_amdgcn_rcpf(-(xs[j * 8 + e * 2] + c));
      float r1 = __builtin_amdgcn_rcpf(-(xs[j * 8 + e * 2 + 1] + c));
      outv[e] = (unsigned)f2bf(r0 * r0) | ((unsigned)f2bf(r1 * r1) << 16);
    }
    *(u32x4*)((char*)wlds + ((cbase + j * 16u) ^ cswz)) = outv;
  }
  __syncthreads();  // barrier 2

  // ---- PV: waves 0..3 only — wave w: O[16][w*16..+16] over full K=1024 ----
  if (w < 4) {
    const int nf = w;
    const u16* vrow = vT + (size_t)(bh * 64 + nf * 16 + lr) * 1024;
    const unsigned swz = (unsigned)(lr & 7) << 4;
    const unsigned abase = (unsigned)(lr * 2048);
    f32x4 oacc = (f32x4){0.f, 0.f, 0.f, 0.f};
#pragma unroll
    for (int ks = 0; ks < 32; ks++) {
      // full-address XOR matching the write-side involution
      bf16x8 afr = *(const bf16x8*)((const char*)wlds +
                                    ((abase + (unsigned)(ks * 64 + g * 16)) ^ swz));
      bf16x8 bfr = *(const bf16x8*)(vrow + ks * 32 + g * 8);
      oacc = __builtin_amdgcn_mfma_f32_16x16x32_bf16(afr, bfr, oacc, 0, 0, 0);
    }
    u16* orow = attn + (size_t)(b * 1024 + q0 + g * 4) * 768 + h * 64 + nf * 16 + lr;
#pragma unroll
    for (int r = 0; r < 4; r++) orow[(size_t)r * 768] = f2bf(oacc[r]);
  }
}

// ---------------- split-K reduce: out = p0+p1+p2+p3 + bias + res ----------------
__global__ __launch_bounds__(256) void splitk_reduce(const float* __restrict__ p,
                                                     const float* __restrict__ bias,
                                                     const float* __restrict__ res,
                                                     float* __restrict__ out) {
  const size_t S = 2048ull * 768;
  size_t i = ((size_t)blockIdx.x * 256 + threadIdx.x) * 4;
  f32x4 v = *(const f32x4*)&p[i];
  v += *(const f32x4*)&p[i + S];
  v += *(const f32x4*)&p[i + 2 * S];
  v += *(const f32x4*)&p[i + 3 * S];
  int col = (int)(i % 768);
  v += *(const f32x4*)&bias[col];
  v += *(const f32x4*)&res[i];
  *(f32x4*)&out[i] = v;
}

// ---------------- pipelined MFMA GEMM: C = A[M][K] * Bt[N][K]^T ----------------
// BM in {64,128}. BM=128: 4 waves as 2x2, BN = 2*WN*16. BM=64: 4 waves as 1x4, BN = 4*WN*16.
// 3-buffer LDS, 2-deep global_load_lds prefetch, counted vmcnt, raw s_barrier (no drain).
// EPI: 0=fused QKV (bias-select + q scale, bf16 out), 1=f32 plain, 2=bf16 plain,
//      3=f32 + bias + residual, 4=GELU(acc+bias) bf16
template <int BM, int WN, int EPI>
__global__ __launch_bounds__(256) void gemm_bt(
    const u16* __restrict__ A, int lda, long long sAb, long long sAh,
    const u16* __restrict__ B0, const u16* __restrict__ B1, const u16* __restrict__ B2,
    int ldb, long long sBb, long long sBh,
    void* __restrict__ Cv, int ldc, long long sCb, long long sCh,
    const float* __restrict__ bias0, const float* __restrict__ bias1,
    const float* __restrict__ bias2, const float* __restrict__ res, int K) {
  constexpr int WCOL = (BM == 128) ? 2 : 4;
  constexpr int BN = WCOL * WN * 16;
  constexpr int NA = BM / 64;
  constexpr int NB = BN / 64;
  constexpr int LT = NA + NB;
  __shared__ __align__(16) u16 lds_a[3][BM * 32];
  __shared__ __align__(16) u16 lds_b[3][BN * 32];

  const int zb = blockIdx.z / 12, zh = blockIdx.z % 12;
  A += zb * sAb + zh * sAh;

  const int colbase = blockIdx.y * BN;
  const u16* B = B0;
  const float* bias = bias0;
  int biasoff = 0;
  float qscale = 1.0f;
  if (EPI == 0) {
    int sel = colbase / 768;
    B = (sel == 0) ? B0 : ((sel == 1) ? B1 : B2);
    bias = (sel == 0) ? bias0 : ((sel == 1) ? bias1 : bias2);
    biasoff = sel * 768;
    qscale = (sel == 0) ? 0.125f : 1.0f;  // 1/sqrt(64) on q only
  }
  B += zb * sBb + zh * sBh;

  const int tid = threadIdx.x;
  const size_t ldab = (size_t)lda * 2, ldbb = (size_t)ldb * 2;
  const char* Abase = (const char*)(A + (size_t)blockIdx.x * BM * lda);
  const char* Bbase = (const char*)(B + (size_t)(colbase - biasoff) * ldb);

  const char* ap[NA];
  const char* bp[NB];
#pragma unroll
  for (int j = 0; j < NA; j++) {
    int lin = (j * 256 + tid) * 16;
    ap[j] = Abase + (size_t)(lin >> 6) * ldab + (lin & 63);
  }
#pragma unroll
  for (int j = 0; j < NB; j++) {
    int lin = (j * 256 + tid) * 16;
    bp[j] = Bbase + (size_t)(lin >> 6) * ldbb + (lin & 63);
  }

  auto stage = [&](int buf) {
#pragma unroll
    for (int j = 0; j < NA; j++) {
      gload16(ap[j], (char*)&lds_a[buf][0] + (j * 256 + tid) * 16);
      ap[j] += 64;
    }
#pragma unroll
    for (int j = 0; j < NB; j++) {
      gload16(bp[j], (char*)&lds_b[buf][0] + (j * 256 + tid) * 16);
      bp[j] += 64;
    }
  };

  f32x4 acc[4][WN];
#pragma unroll
  for (int m = 0; m < 4; m++)
#pragma unroll
    for (int n = 0; n < WN; n++) acc[m][n] = (f32x4){0.f, 0.f, 0.f, 0.f};

  const int w = tid >> 6, l = tid & 63;
  const int wm = (BM == 128) ? (w >> 1) : 0;
  const int wn = (BM == 128) ? (w & 1) : w;
  const int lr = l & 15, kg = l >> 4;

  const int nt = K / 32;
  stage(0);
  if (nt > 1) stage(1);

  for (int t = 0; t < nt; ++t) {
    const int buf = t % 3;
    if (t + 2 < nt) {
      stage((t + 2) % 3);
      vm_wait<2 * LT>();
    } else if (t + 1 < nt) {
      vm_wait<LT>();
    } else {
      vm_wait<0>();
    }
    __builtin_amdgcn_sched_barrier(0);
    __builtin_amdgcn_s_barrier();
    __builtin_amdgcn_sched_barrier(0);

    bf16x8 af[4], bfr[WN];
#pragma unroll
    for (int m = 0; m < 4; m++)
      af[m] = *(const bf16x8*)&lds_a[buf][(wm * 64 + m * 16 + lr) * 32 + kg * 8];
#pragma unroll
    for (int n = 0; n < WN; n++)
      bfr[n] = *(const bf16x8*)&lds_b[buf][(wn * WN * 16 + n * 16 + lr) * 32 + kg * 8];
#pragma unroll
    for (int m = 0; m < 4; m++)
#pragma unroll
      for (int n = 0; n < WN; n++)
        acc[m][n] = __builtin_amdgcn_mfma_f32_16x16x32_bf16(af[m], bfr[n], acc[m][n], 0, 0, 0);

    __builtin_amdgcn_sched_barrier(0);
    __builtin_amdgcn_s_barrier();
    __builtin_amdgcn_sched_barrier(0);
  }

  const int row0 = blockIdx.x * BM + ((BM == 128) ? wm * 64 : 0) + kg * 4;
  const int colb = colbase + wn * WN * 16;
  float* Cf = (float*)Cv + (size_t)zb * sCb + (size_t)zh * sCh;
  u16* Cu = (u16*)Cv + (size_t)zb * sCb + (size_t)zh * sCh;
#pragma unroll
  for (int m = 0; m < 4; m++) {
#pragma unroll
    for (int n = 0; n < WN; n++) {
#pragma unroll
      for (int r = 0; r < 4; r++) {
        int row = row0 + m * 16 + r;
        int col = colb + n * 16 + lr;
        size_t idx = (size_t)row * ldc + col;
        float v = acc[m][n][r];
        if (EPI == 0) {
          Cu[idx] = f2bf((v + bias[col - biasoff]) * qscale);
        } else if (EPI == 1) {
          Cf[idx] = v;
        } else if (EPI == 2) {
          Cu[idx] = f2bf(v);
        } else if (EPI == 3) {
          Cf[idx] = v + bias[col] + res[idx];
        } else {  // exact GELU
          v += bias[col];
          Cu[idx] = f2bf(0.5f * v * (1.0f + erff(v * 0.70710678118654752f)));
        }
      }
    }
  }
}

extern "C" void kernel_launch(void* const* d_in, const int* in_sizes, int n_in,
                              void* d_out, int out_size, void* d_ws, size_t ws_size,
                              hipStream_t stream) {
  const float* x     = (const float*)d_in[0];
  const float* ln1_g = (const float*)d_in[1];
  const float* ln1_b = (const float*)d_in[2];
  const float* wq    = (const float*)d_in[3];
  const float* bq    = (const float*)d_in[4];
  const float* wk    = (const float*)d_in[5];
  const float* bk    = (const float*)d_in[6];
  const float* wv    = (const float*)d_in[7];
  const float* bv    = (const float*)d_in[8];
  const float* wo    = (const float*)d_in[9];
  const float* bo    = (const float*)d_in[10];
  const float* ln2_g = (const float*)d_in[11];
  const float* ln2_b = (const float*)d_in[12];
  const float* w1    = (const float*)d_in[13];
  const float* b1    = (const float*)d_in[14];
  const float* w2    = (const float*)d_in[15];
  const float* b2    = (const float*)d_in[16];
  float* out = (float*)d_out;

  char* p = (char*)d_ws;
  auto alloc = [&](size_t n) { char* r = p; p += (n + 255) & ~(size_t)255; return r; };
  u16*   qkv    = (u16*)  alloc(2048ull * 2304 * 2);       // [b*1024+s][2304] q|k|v bf16
  u16*   y1     = (u16*)  alloc(2048ull * 768 * 2);
  u16*   vT     = (u16*)  alloc(24ull * 64 * 1024 * 2);    // [(b*12+h)*64+d][1024]
  u16*   attn   = (u16*)  alloc(2048ull * 768 * 2);
  float* x1     = (float*)alloc(2048ull * 768 * 4);
  u16*   y2     = (u16*)  alloc(2048ull * 768 * 2);
  u16*   hbuf   = (u16*)  alloc(2048ull * 3072 * 2);
  float* pbuf   = (float*)alloc(4ull * 2048 * 768 * 4);    // split-K partials
  u16*   wq_t   = (u16*)  alloc(768ull * 768 * 2);
  u16*   wk_t   = (u16*)  alloc(768ull * 768 * 2);
  u16*   wv_t   = (u16*)  alloc(768ull * 768 * 2);
  u16*   wo_t   = (u16*)  alloc(768ull * 768 * 2);
  u16*   w1_t   = (u16*)  alloc(3072ull * 768 * 2);
  u16*   w2_t   = (u16*)  alloc(768ull * 3072 * 2);
  (void)in_sizes; (void)n_in; (void)out_size; (void)ws_size;

  // weights -> bf16 [N][K]
  wt_transpose<<<dim3(24, 24), 256, 0, stream>>>(wq, wq_t, 768, 768);
  wt_transpose<<<dim3(24, 24), 256, 0, stream>>>(wk, wk_t, 768, 768);
  wt_transpose<<<dim3(24, 24), 256, 0, stream>>>(wv, wv_t, 768, 768);
  wt_transpose<<<dim3(24, 24), 256, 0, stream>>>(wo, wo_t, 768, 768);
  wt_transpose<<<dim3(96, 24), 256, 0, stream>>>(w1, w1_t, 768, 3072);
  wt_transpose<<<dim3(24, 96), 256, 0, stream>>>(w2, w2_t, 3072, 768);

  // LN1
  ln_kernel<<<2048, 256, 0, stream>>>(x, ln1_g, ln1_b, y1);

  // fused QKV projection: [2048,768] x [768,2304] -> qkv bf16 (q scaled by 1/8)
  gemm_bt<128, 4, 0><<<dim3(16, 18, 1), 256, 0, stream>>>(
      y1, 768, 0, 0, wq_t, wk_t, wv_t, 768, 0, 0, qkv, 2304, 0, 0, bq, bk, bv, nullptr, 768);

  // V transpose
  v_transpose<<<dim3(32, 2, 24), 256, 0, stream>>>(qkv, vT);

  // fused poly-norm attention: QK^T + Newton + PV, scores never touch HBM
  fused_attn<<<dim3(64, 24), 512, 0, stream>>>(qkv, vT, attn);

  // x1 = x + attn @ wo + bo
  gemm_bt<64, 2, 3><<<dim3(32, 6, 1), 256, 0, stream>>>(
      attn, 768, 0, 0, wo_t, nullptr, nullptr, 768, 0, 0, x1, 768, 0, 0,
      bo, nullptr, nullptr, x, 768);

  // LN2
  ln_kernel<<<2048, 256, 0, stream>>>(x1, ln2_g, ln2_b, y2);

  // h = gelu(y2 @ w1 + b1)
  gemm_bt<128, 4, 4><<<dim3(16, 24, 1), 256, 0, stream>>>(
      y2, 768, 0, 0, w1_t, nullptr, nullptr, 768, 0, 0, hbuf, 3072, 0, 0,
      b1, nullptr, nullptr, nullptr, 768);

  // MLP2 split-K x4: partials = h[:, z*768:(z+1)*768] @ w2_t[:, z*768:(z+1)*768]^T
  gemm_bt<64, 2, 1><<<dim3(32, 6, 4), 256, 0, stream>>>(
      hbuf, 3072, 0, 768LL, w2_t, nullptr, nullptr, 3072, 0, 768LL,
      pbuf, 768, 0, 1572864LL, nullptr, nullptr, nullptr, nullptr, 768);

  // out = sum(partials) + b2 + x1
  splitk_reduce<<<1536, 256, 0, stream>>>(pbuf, b2, x1, out);
}

// Round 9
// 170.187 us; speedup vs baseline: 1.9988x; 1.0737x over previous
//
#include <hip/hip_runtime.h>

#define DEV __device__ __forceinline__

typedef unsigned short u16;
typedef __attribute__((ext_vector_type(8))) short bf16x8;
typedef __attribute__((ext_vector_type(4))) float f32x4;
typedef __attribute__((ext_vector_type(4))) unsigned int u32x4;

// round-to-nearest-even f32 -> bf16
DEV u16 f2bf(float f) {
  union { float f; unsigned u; } un; un.f = f;
  unsigned r = un.u + 0x7fffu + ((un.u >> 16) & 1u);
  return (u16)(r >> 16);
}

DEV void gload16(const void* g, void* l) {
  __builtin_amdgcn_global_load_lds((const __attribute__((address_space(1))) void*)g,
                                   (__attribute__((address_space(3))) void*)l, 16, 0, 0);
}

template <int N>
DEV void vm_wait() { asm volatile("s_waitcnt vmcnt(%0)" :: "n"(N) : "memory"); }

DEV float blk_sum(float v, volatile float* sb) {
#pragma unroll
  for (int o = 32; o; o >>= 1) v += __shfl_xor(v, o);
  __syncthreads();
  if ((threadIdx.x & 63) == 0) sb[threadIdx.x >> 6] = v;
  __syncthreads();
  return sb[0] + sb[1] + sb[2] + sb[3];
}

// ---------------- LayerNorm (row = 768) -> bf16 ----------------
__global__ __launch_bounds__(256) void ln_kernel(const float* __restrict__ x,
                                                 const float* __restrict__ g,
                                                 const float* __restrict__ b,
                                                 u16* __restrict__ y) {
  __shared__ float sb[4];
  const size_t row = blockIdx.x;
  const float* xr = x + row * 768;
  const int t = threadIdx.x;
  float v0 = xr[t], v1 = xr[t + 256], v2 = xr[t + 512];
  float mean = blk_sum(v0 + v1 + v2, sb) * (1.0f / 768.0f);
  float d0 = v0 - mean, d1 = v1 - mean, d2 = v2 - mean;
  float var = blk_sum(d0 * d0 + d1 * d1 + d2 * d2, sb) * (1.0f / 768.0f);
  float inv = rsqrtf(var + 1e-5f);
  u16* yr = y + row * 768;
  yr[t]       = f2bf(d0 * inv * g[t]       + b[t]);
  yr[t + 256] = f2bf(d1 * inv * g[t + 256] + b[t + 256]);
  yr[t + 512] = f2bf(d2 * inv * g[t + 512] + b[t + 512]);
}

// ---------------- all-weights transpose+convert in ONE dispatch ----------------
// in[K][N] f32 -> out[N][K] bf16 for {wq,wk,wv,wo,w1,w2}. 6912 32x32 tiles:
// ids 0..2303: wq/wk/wv/wo (576 each, 768x768); 2304..4607: w1 (768x3072);
// 4608..6911: w2 (3072x768).
__global__ __launch_bounds__(256) void wt_all(
    const float* __restrict__ wq, const float* __restrict__ wk,
    const float* __restrict__ wv, const float* __restrict__ wo,
    const float* __restrict__ w1, const float* __restrict__ w2,
    u16* __restrict__ oq, u16* __restrict__ ok, u16* __restrict__ ov,
    u16* __restrict__ oo, u16* __restrict__ o1, u16* __restrict__ o2) {
  __shared__ float tile[32][33];
  const int id = blockIdx.x;
  const float* in;
  u16* out;
  int K, N, t, nx;
  if (id < 2304) {
    int s = id / 576;
    t = id % 576;
    K = 768; N = 768; nx = 24;
    in  = (s == 0) ? wq : (s == 1) ? wk : (s == 2) ? wv : wo;
    out = (s == 0) ? oq : (s == 1) ? ok : (s == 2) ? ov : oo;
  } else if (id < 4608) {
    t = id - 2304; in = w1; out = o1; K = 768; N = 3072; nx = 96;
  } else {
    t = id - 4608; in = w2; out = o2; K = 3072; N = 768; nx = 24;
  }
  const int yt = (nx == 96) ? (t / 96) : (t / 24);
  const int xt = t - yt * nx;
  const int n0 = xt * 32, k0 = yt * 32;
  const int tx = threadIdx.x & 31, ty = threadIdx.x >> 5;
#pragma unroll
  for (int i = 0; i < 4; i++)
    tile[ty + 8 * i][tx] = in[(size_t)(k0 + ty + 8 * i) * N + n0 + tx];
  __syncthreads();
#pragma unroll
  for (int i = 0; i < 4; i++)
    out[(size_t)(n0 + ty + 8 * i) * K + k0 + tx] = f2bf(tile[tx][ty + 8 * i]);
}

// ---------------- fused poly-norm attention (chunk-redistributed Newton) ----------------
// Grid: (64 q-tiles, 24 b*h). Block: 512 thr = 8 waves. Only 2 barriers total.
// Phase 1: wave w computes scores[0..15][w*128..+127] via MFMA, scatters bf16 scores
//          into the swizzled 32KB LDS tile. BARRIER.
// Phase 2: thread owns row=tid>>5, cols (tid&31)*32..+31 (4x ds_read_b128, same XOR
//          involution). Row max + 6 Newton iterations run entirely in-register with
//          half-wave (32-lane) shfl reduces — zero barriers, zero LDS traffic.
//          Weights written back in place to the same addresses. BARRIER.
// Phase 3: waves 0..3 do PV over full K=1024 (R7-proven shape); waves 4..7 exit.
__global__ __launch_bounds__(512) void fused_attn(const u16* __restrict__ qkv,
                                                  const u16* __restrict__ vT,
                                                  u16* __restrict__ attn) {
  __shared__ __align__(16) u16 wlds[16 * 1024];  // 32KB, XOR-swizzled (scores, then weights)

  const int tid = threadIdx.x;
  const int w = tid >> 6, l = tid & 63;
  const int g = l >> 4, lr = l & 15;
  const int bh = blockIdx.y, b = bh / 12, h = bh % 12;
  const int q0 = blockIdx.x * 16;

  // ---- QK^T (q pre-scaled by 1/8 in the QKV GEMM) ----
  const u16* qrow = qkv + (size_t)(b * 1024 + q0 + lr) * 2304 + h * 64;
  const u16* krow = qkv + (size_t)(b * 1024 + w * 128 + lr) * 2304 + 768 + h * 64;

  bf16x8 af[2];
  af[0] = *(const bf16x8*)(qrow + g * 8);
  af[1] = *(const bf16x8*)(qrow + 32 + g * 8);

  f32x4 acc[8];
#pragma unroll
  for (int n = 0; n < 8; n++) acc[n] = (f32x4){0.f, 0.f, 0.f, 0.f};

#pragma unroll
  for (int n = 0; n < 8; n++) {
    bf16x8 b0 = *(const bf16x8*)(krow + n * 16 * 2304 + g * 8);
    bf16x8 b1 = *(const bf16x8*)(krow + n * 16 * 2304 + 32 + g * 8);
    acc[n] = __builtin_amdgcn_mfma_f32_16x16x32_bf16(af[0], b0, acc[n], 0, 0, 0);
    acc[n] = __builtin_amdgcn_mfma_f32_16x16x32_bf16(af[1], b1, acc[n], 0, 0, 0);
  }
  // lane holds scores for rows g*4 + r (q-local), cols w*128 + n*16 + lr

  // ---- scatter scores (bf16) into swizzled LDS ----
#pragma unroll
  for (int n = 0; n < 8; n++)
#pragma unroll
    for (int r = 0; r < 4; r++) {
      int row = g * 4 + r;
      int col = w * 128 + n * 16 + lr;
      unsigned off = (unsigned)(row * 2048 + col * 2);
      off ^= (unsigned)(row & 7) << 4;
      *(u16*)((char*)wlds + off) = f2bf(acc[n][r]);
    }
  __syncthreads();  // barrier 1

  // ---- chunk read: thread owns row = tid>>5, cols (tid&31)*32 .. +31 ----
  const int crow = tid >> 5, l32 = tid & 31;
  const unsigned cswz = (unsigned)(crow & 7) << 4;
  const unsigned cbase = (unsigned)(crow * 2048 + l32 * 64);
  float xs[32];
#pragma unroll
  for (int j = 0; j < 4; j++) {
    u32x4 raw = *(const u32x4*)((const char*)wlds + ((cbase + j * 16u) ^ cswz));
#pragma unroll
    for (int e = 0; e < 4; e++) {
      union { unsigned u; float f; } lo, hi;
      lo.u = raw[e] << 16;
      hi.u = raw[e] & 0xffff0000u;
      xs[j * 8 + e * 2] = lo.f;
      xs[j * 8 + e * 2 + 1] = hi.f;
    }
  }

  // ---- row max (31 fmax + 5 half-wave shfl) -> c0 = -max - 1 ----
  float mx = xs[0];
#pragma unroll
  for (int i = 1; i < 32; i++) mx = fmaxf(mx, xs[i]);
#pragma unroll
  for (int o = 1; o < 32; o <<= 1) mx = fmaxf(mx, __shfl_xor(mx, o));
  float c = -mx - 1.0f;

  // ---- 6 Newton iterations: fully in-register, zero barriers ----
#pragma unroll 1
  for (int it = 0; it < 6; it++) {
    float s2 = 0.f, s3 = 0.f;
#pragma unroll
    for (int i = 0; i < 32; i++) {
      float rr = __builtin_amdgcn_rcpf(-(xs[i] + c));  // 1/base, base >= 1
      float r2 = rr * rr;
      s2 += r2;
      s3 = fmaf(r2, rr, s3);
    }
#pragma unroll
    for (int o = 1; o < 32; o <<= 1) {
      s2 += __shfl_xor(s2, o);
      s3 += __shfl_xor(s3, o);
    }
    c -= (s2 - 1.0f) * __builtin_amdgcn_rcpf(2.0f * s3 + 1e-8f);
  }

  // ---- weights = base^-2 -> bf16, written back in place (same addresses) ----
#pragma unroll
  for (int j = 0; j < 4; j++) {
    u32x4 outv;
#pragma unroll
    for (int e = 0; e < 4; e++) {
      float r0 = __builtin_amdgcn_rcpf(-(xs[j * 8 + e * 2] + c));
      float r1 = __builtin_amdgcn_rcpf(-(xs[j * 8 + e * 2 + 1] + c));
      outv[e] = (unsigned)f2bf(r0 * r0) | ((unsigned)f2bf(r1 * r1) << 16);
    }
    *(u32x4*)((char*)wlds + ((cbase + j * 16u) ^ cswz)) = outv;
  }
  __syncthreads();  // barrier 2

  // ---- PV: waves 0..3 only — wave w: O[16][w*16..+16] over full K=1024 ----
  if (w < 4) {
    const int nf = w;
    const u16* vrow = vT + (size_t)(bh * 64 + nf * 16 + lr) * 1024;
    const unsigned swz = (unsigned)(lr & 7) << 4;
    const unsigned abase = (unsigned)(lr * 2048);
    f32x4 oacc = (f32x4){0.f, 0.f, 0.f, 0.f};
#pragma unroll
    for (int ks = 0; ks < 32; ks++) {
      // full-address XOR matching the write-side involution
      bf16x8 afr = *(const bf16x8*)((const char*)wlds +
                                    ((abase + (unsigned)(ks * 64 + g * 16)) ^ swz));
      bf16x8 bfr = *(const bf16x8*)(vrow + ks * 32 + g * 8);
      oacc = __builtin_amdgcn_mfma_f32_16x16x32_bf16(afr, bfr, oacc, 0, 0, 0);
    }
    u16* orow = attn + (size_t)(b * 1024 + q0 + g * 4) * 768 + h * 64 + nf * 16 + lr;
#pragma unroll
    for (int r = 0; r < 4; r++) orow[(size_t)r * 768] = f2bf(oacc[r]);
  }
}

// ---------------- split-K reduce: out = p0+p1+p2+p3 + bias + res ----------------
__global__ __launch_bounds__(256) void splitk_reduce(const float* __restrict__ p,
                                                     const float* __restrict__ bias,
                                                     const float* __restrict__ res,
                                                     float* __restrict__ out) {
  const size_t S = 2048ull * 768;
  size_t i = ((size_t)blockIdx.x * 256 + threadIdx.x) * 4;
  f32x4 v = *(const f32x4*)&p[i];
  v += *(const f32x4*)&p[i + S];
  v += *(const f32x4*)&p[i + 2 * S];
  v += *(const f32x4*)&p[i + 3 * S];
  int col = (int)(i % 768);
  v += *(const f32x4*)&bias[col];
  v += *(const f32x4*)&res[i];
  *(f32x4*)&out[i] = v;
}

// ---------------- pipelined MFMA GEMM: C = A[M][K] * Bt[N][K]^T ----------------
// BM in {64,128}. BM=128: 4 waves as 2x2, BN = 2*WN*16. BM=64: 4 waves as 1x4, BN = 4*WN*16.
// 3-buffer LDS, 2-deep global_load_lds prefetch, counted vmcnt, raw s_barrier (no drain).
// EPI: 0=fused QKV (bias-select + q scale, bf16 out; v-blocks scatter into vT via 'res'),
//      1=f32 plain, 2=bf16 plain, 3=f32 + bias + residual, 4=GELU(acc+bias) bf16
template <int BM, int WN, int EPI>
__global__ __launch_bounds__(256) void gemm_bt(
    const u16* __restrict__ A, int lda, long long sAb, long long sAh,
    const u16* __restrict__ B0, const u16* __restrict__ B1, const u16* __restrict__ B2,
    int ldb, long long sBb, long long sBh,
    void* __restrict__ Cv, int ldc, long long sCb, long long sCh,
    const float* __restrict__ bias0, const float* __restrict__ bias1,
    const float* __restrict__ bias2, const float* __restrict__ res, int K) {
  constexpr int WCOL = (BM == 128) ? 2 : 4;
  constexpr int BN = WCOL * WN * 16;
  constexpr int NA = BM / 64;
  constexpr int NB = BN / 64;
  constexpr int LT = NA + NB;
  __shared__ __align__(16) u16 lds_a[3][BM * 32];
  __shared__ __align__(16) u16 lds_b[3][BN * 32];

  const int zb = blockIdx.z / 12, zh = blockIdx.z % 12;
  A += zb * sAb + zh * sAh;

  const int colbase = blockIdx.y * BN;
  const u16* B = B0;
  const float* bias = bias0;
  int biasoff = 0;
  float qscale = 1.0f;
  int sel = 0;
  if (EPI == 0) {
    sel = colbase / 768;
    B = (sel == 0) ? B0 : ((sel == 1) ? B1 : B2);
    bias = (sel == 0) ? bias0 : ((sel == 1) ? bias1 : bias2);
    biasoff = sel * 768;
    qscale = (sel == 0) ? 0.125f : 1.0f;  // 1/sqrt(64) on q only
  }
  B += zb * sBb + zh * sBh;

  const int tid = threadIdx.x;
  const size_t ldab = (size_t)lda * 2, ldbb = (size_t)ldb * 2;
  const char* Abase = (const char*)(A + (size_t)blockIdx.x * BM * lda);
  const char* Bbase = (const char*)(B + (size_t)(colbase - biasoff) * ldb);

  const char* ap[NA];
  const char* bp[NB];
#pragma unroll
  for (int j = 0; j < NA; j++) {
    int lin = (j * 256 + tid) * 16;
    ap[j] = Abase + (size_t)(lin >> 6) * ldab + (lin & 63);
  }
#pragma unroll
  for (int j = 0; j < NB; j++) {
    int lin = (j * 256 + tid) * 16;
    bp[j] = Bbase + (size_t)(lin >> 6) * ldbb + (lin & 63);
  }

  auto stage = [&](int buf) {
#pragma unroll
    for (int j = 0; j < NA; j++) {
      gload16(ap[j], (char*)&lds_a[buf][0] + (j * 256 + tid) * 16);
      ap[j] += 64;
    }
#pragma unroll
    for (int j = 0; j < NB; j++) {
      gload16(bp[j], (char*)&lds_b[buf][0] + (j * 256 + tid) * 16);
      bp[j] += 64;
    }
  };

  f32x4 acc[4][WN];
#pragma unroll
  for (int m = 0; m < 4; m++)
#pragma unroll
    for (int n = 0; n < WN; n++) acc[m][n] = (f32x4){0.f, 0.f, 0.f, 0.f};

  const int w = tid >> 6, l = tid & 63;
  const int wm = (BM == 128) ? (w >> 1) : 0;
  const int wn = (BM == 128) ? (w & 1) : w;
  const int lr = l & 15, kg = l >> 4;

  const int nt = K / 32;
  stage(0);
  if (nt > 1) stage(1);

  for (int t = 0; t < nt; ++t) {
    const int buf = t % 3;
    if (t + 2 < nt) {
      stage((t + 2) % 3);
      vm_wait<2 * LT>();
    } else if (t + 1 < nt) {
      vm_wait<LT>();
    } else {
      vm_wait<0>();
    }
    __builtin_amdgcn_sched_barrier(0);
    __builtin_amdgcn_s_barrier();
    __builtin_amdgcn_sched_barrier(0);

    bf16x8 af[4], bfr[WN];
#pragma unroll
    for (int m = 0; m < 4; m++)
      af[m] = *(const bf16x8*)&lds_a[buf][(wm * 64 + m * 16 + lr) * 32 + kg * 8];
#pragma unroll
    for (int n = 0; n < WN; n++)
      bfr[n] = *(const bf16x8*)&lds_b[buf][(wn * WN * 16 + n * 16 + lr) * 32 + kg * 8];
#pragma unroll
    for (int m = 0; m < 4; m++)
#pragma unroll
      for (int n = 0; n < WN; n++)
        acc[m][n] = __builtin_amdgcn_mfma_f32_16x16x32_bf16(af[m], bfr[n], acc[m][n], 0, 0, 0);

    __builtin_amdgcn_sched_barrier(0);
    __builtin_amdgcn_s_barrier();
    __builtin_amdgcn_sched_barrier(0);
  }

  const int row0 = blockIdx.x * BM + ((BM == 128) ? wm * 64 : 0) + kg * 4;
  const int colb = colbase + wn * WN * 16;
  float* Cf = (float*)Cv + (size_t)zb * sCb + (size_t)zh * sCh;
  u16* Cu = (u16*)Cv + (size_t)zb * sCb + (size_t)zh * sCh;

  if (EPI == 0 && sel == 2) {
    // v-blocks: scatter directly into vT[(b*12+h)*64+d][s] (bit-identical values)
    u16* vTp = (u16*)res;
#pragma unroll
    for (int m = 0; m < 4; m++) {
#pragma unroll
      for (int n = 0; n < WN; n++) {
#pragma unroll
        for (int r = 0; r < 4; r++) {
          int row = row0 + m * 16 + r;          // b*1024 + s
          int col = colb + n * 16 + lr;         // 1536 + h*64 + d
          int cv = col - 1536;
          int bb = row >> 10, ss = row & 1023;
          int hh = cv >> 6, dd = cv & 63;
          vTp[(size_t)((bb * 12 + hh) * 64 + dd) * 1024 + ss] =
              f2bf(acc[m][n][r] + bias[cv]);
        }
      }
    }
    return;
  }

#pragma unroll
  for (int m = 0; m < 4; m++) {
#pragma unroll
    for (int n = 0; n < WN; n++) {
#pragma unroll
      for (int r = 0; r < 4; r++) {
        int row = row0 + m * 16 + r;
        int col = colb + n * 16 + lr;
        size_t idx = (size_t)row * ldc + col;
        float v = acc[m][n][r];
        if (EPI == 0) {
          Cu[idx] = f2bf((v + bias[col - biasoff]) * qscale);
        } else if (EPI == 1) {
          Cf[idx] = v;
        } else if (EPI == 2) {
          Cu[idx] = f2bf(v);
        } else if (EPI == 3) {
          Cf[idx] = v + bias[col] + res[idx];
        } else {  // exact GELU
          v += bias[col];
          Cu[idx] = f2bf(0.5f * v * (1.0f + erff(v * 0.70710678118654752f)));
        }
      }
    }
  }
}

extern "C" void kernel_launch(void* const* d_in, const int* in_sizes, int n_in,
                              void* d_out, int out_size, void* d_ws, size_t ws_size,
                              hipStream_t stream) {
  const float* x     = (const float*)d_in[0];
  const float* ln1_g = (const float*)d_in[1];
  const float* ln1_b = (const float*)d_in[2];
  const float* wq    = (const float*)d_in[3];
  const float* bq    = (const float*)d_in[4];
  const float* wk    = (const float*)d_in[5];
  const float* bk    = (const float*)d_in[6];
  const float* wv    = (const float*)d_in[7];
  const float* bv    = (const float*)d_in[8];
  const float* wo    = (const float*)d_in[9];
  const float* bo    = (const float*)d_in[10];
  const float* ln2_g = (const float*)d_in[11];
  const float* ln2_b = (const float*)d_in[12];
  const float* w1    = (const float*)d_in[13];
  const float* b1    = (const float*)d_in[14];
  const float* w2    = (const float*)d_in[15];
  const float* b2    = (const float*)d_in[16];
  float* out = (float*)d_out;

  char* p = (char*)d_ws;
  auto alloc = [&](size_t n) { char* r = p; p += (n + 255) & ~(size_t)255; return r; };
  u16*   qkv    = (u16*)  alloc(2048ull * 2304 * 2);       // [b*1024+s][2304] q|k (v unused)
  u16*   y1     = (u16*)  alloc(2048ull * 768 * 2);
  u16*   vT     = (u16*)  alloc(24ull * 64 * 1024 * 2);    // [(b*12+h)*64+d][1024]
  u16*   attn   = (u16*)  alloc(2048ull * 768 * 2);
  float* x1     = (float*)alloc(2048ull * 768 * 4);
  u16*   y2     = (u16*)  alloc(2048ull * 768 * 2);
  u16*   hbuf   = (u16*)  alloc(2048ull * 3072 * 2);
  float* pbuf   = (float*)alloc(4ull * 2048 * 768 * 4);    // split-K partials
  u16*   wq_t   = (u16*)  alloc(768ull * 768 * 2);
  u16*   wk_t   = (u16*)  alloc(768ull * 768 * 2);
  u16*   wv_t   = (u16*)  alloc(768ull * 768 * 2);
  u16*   wo_t   = (u16*)  alloc(768ull * 768 * 2);
  u16*   w1_t   = (u16*)  alloc(3072ull * 768 * 2);
  u16*   w2_t   = (u16*)  alloc(768ull * 3072 * 2);
  (void)in_sizes; (void)n_in; (void)out_size; (void)ws_size;

  // all weights -> bf16 [N][K], one dispatch
  wt_all<<<6912, 256, 0, stream>>>(wq, wk, wv, wo, w1, w2,
                                   wq_t, wk_t, wv_t, wo_t, w1_t, w2_t);

  // LN1
  ln_kernel<<<2048, 256, 0, stream>>>(x, ln1_g, ln1_b, y1);

  // fused QKV projection: [2048,768] x [768,2304]; q scaled by 1/8; v-blocks scatter to vT
  gemm_bt<128, 4, 0><<<dim3(16, 18, 1), 256, 0, stream>>>(
      y1, 768, 0, 0, wq_t, wk_t, wv_t, 768, 0, 0, qkv, 2304, 0, 0,
      bq, bk, bv, (const float*)vT, 768);

  // fused poly-norm attention: QK^T + Newton + PV, scores never touch HBM
  fused_attn<<<dim3(64, 24), 512, 0, stream>>>(qkv, vT, attn);

  // x1 = x + attn @ wo + bo
  gemm_bt<64, 2, 3><<<dim3(32, 6, 1), 256, 0, stream>>>(
      attn, 768, 0, 0, wo_t, nullptr, nullptr, 768, 0, 0, x1, 768, 0, 0,
      bo, nullptr, nullptr, x, 768);

  // LN2
  ln_kernel<<<2048, 256, 0, stream>>>(x1, ln2_g, ln2_b, y2);

  // h = gelu(y2 @ w1 + b1)
  gemm_bt<128, 4, 4><<<dim3(16, 24, 1), 256, 0, stream>>>(
      y2, 768, 0, 0, w1_t, nullptr, nullptr, 768, 0, 0, hbuf, 3072, 0, 0,
      b1, nullptr, nullptr, nullptr, 768);

  // MLP2 split-K x4: partials = h[:, z*768:(z+1)*768] @ w2_t[:, z*768:(z+1)*768]^T
  gemm_bt<64, 2, 1><<<dim3(32, 6, 4), 256, 0, stream>>>(
      hbuf, 3072, 0, 768LL, w2_t, nullptr, nullptr, 3072, 0, 768LL,
      pbuf, 768, 0, 1572864LL, nullptr, nullptr, nullptr, nullptr, 768);

  // out = sum(partials) + b2 + x1
  splitk_reduce<<<1536, 256, 0, stream>>>(pbuf, b2, x1, out);
}